// Round 1
// baseline (2341.986 us; speedup 1.0000x reference)
//
#include <hip/hip_runtime.h>
#include <hip/hip_bf16.h>
#include <cstdint>
#include <cstddef>

#define NT 200000
#define NP 5000
#define FDIM 384
#define CDIM 128
#define EC 600000
#define EL 400000

// ---------------- CSR build (counting sort) ----------------
__global__ void k_hist(const int* __restrict__ keys, int n, int* __restrict__ counts){
  int i = blockIdx.x*256 + threadIdx.x;
  if (i < n) atomicAdd(&counts[keys[i]], 1);
}

__global__ void k_partial(const int* __restrict__ counts, int n, int* __restrict__ partials){
  __shared__ int s[256];
  int i = blockIdx.x*256 + threadIdx.x;
  s[threadIdx.x] = (i < n) ? counts[i] : 0;
  __syncthreads();
  for (int off = 128; off > 0; off >>= 1){
    if (threadIdx.x < off) s[threadIdx.x] += s[threadIdx.x + off];
    __syncthreads();
  }
  if (threadIdx.x == 0) partials[blockIdx.x] = s[0];
}

// single block: in-place exclusive scan of partials, write grand total to *total_out
__global__ void k_scan_partials(int* __restrict__ partials, int nP, int* __restrict__ total_out){
  __shared__ int s[1024];
  int carry = 0;
  for (int base = 0; base < nP; base += 1024){
    int i = base + threadIdx.x;
    int v = (i < nP) ? partials[i] : 0;
    s[threadIdx.x] = v; __syncthreads();
    for (int off = 1; off < 1024; off <<= 1){
      int t = (threadIdx.x >= off) ? s[threadIdx.x - off] : 0;
      __syncthreads();
      s[threadIdx.x] += t;
      __syncthreads();
    }
    if (i < nP) partials[i] = carry + s[threadIdx.x] - v;  // exclusive
    int chunk_total = s[1023];
    __syncthreads();
    carry += chunk_total;
  }
  if (threadIdx.x == 0 && total_out) *total_out = carry;
}

__global__ void k_scan_final(const int* __restrict__ counts, const int* __restrict__ pscan,
                             int n, int* __restrict__ rowptr){
  __shared__ int s[256];
  int tid = threadIdx.x;
  int i = blockIdx.x*256 + tid;
  int v = (i < n) ? counts[i] : 0;
  s[tid] = v; __syncthreads();
  for (int off = 1; off < 256; off <<= 1){
    int t = (tid >= off) ? s[tid - off] : 0;
    __syncthreads();
    s[tid] += t;
    __syncthreads();
  }
  if (i < n) rowptr[i] = pscan[blockIdx.x] + s[tid] - v;
}

__global__ void k_copy_int(const int* __restrict__ src, int* __restrict__ dst, int n){
  int i = blockIdx.x*256 + threadIdx.x;
  if (i < n) dst[i] = src[i];
}

__global__ void k_fill(const int* __restrict__ keys, const int* __restrict__ storev,
                       int n, int* __restrict__ cursor, int* __restrict__ vals){
  int e = blockIdx.x*256 + threadIdx.x;
  if (e < n){
    int k = keys[e];
    int pos = atomicAdd(&cursor[k], 1);
    vals[pos] = storev ? storev[e] : e;
  }
}

// ---------------- xp init (gather, pid is identity but be general) ----------------
__global__ void k_xp_init(const float* __restrict__ pe, const int* __restrict__ pid,
                          float* __restrict__ xp){
  int i = blockIdx.x*256 + threadIdx.x;
  if (i < NP*CDIM){
    int p = i >> 7, c = i & 127;
    xp[i] = pe[(size_t)pid[p]*CDIM + c];
  }
}

// ---------------- weight combine per layer ----------------
// Wp [384,128] = [Wl0 ; Wl1 ; Wr0+Wr1], bp = bl0+bl1
// Wt [128,128] = Wr2+Wr3,               bt = bl2+bl3
__global__ void k_wcombine(const float* __restrict__ gWl, const float* __restrict__ gbl,
                           const float* __restrict__ gWr, int layer,
                           float* __restrict__ Wp, float* __restrict__ bp,
                           float* __restrict__ Wt, float* __restrict__ bt){
  int i = blockIdx.x*256 + threadIdx.x;
  const float* Wl_l = gWl + (size_t)layer*4*16384;
  const float* Wr_l = gWr + (size_t)layer*4*16384;
  const float* bl_l = gbl + (size_t)layer*4*128;
  if (i < 16384){
    Wp[i]          = Wl_l[i];
    Wp[16384 + i]  = Wl_l[16384 + i];
    Wp[32768 + i]  = Wr_l[i] + Wr_l[16384 + i];
    Wt[i]          = Wr_l[2*16384 + i] + Wr_l[3*16384 + i];
  }
  if (i < 128){
    bp[i] = bl_l[i] + bl_l[128 + i];
    bt[i] = bl_l[2*128 + i] + bl_l[3*128 + i];
  }
}

// ---------------- segment sums into apcat = [a0 | a1 | xp] (NP x 384) ----------------
__global__ __launch_bounds__(128) void k_segsum(
    const float* __restrict__ xt, const float* __restrict__ xp,
    const int* __restrict__ mrp, const int* __restrict__ mv,
    const int* __restrict__ crp, const int* __restrict__ cv,
    float* __restrict__ apcat){
  int p = blockIdx.x, c = threadIdx.x;
  float s0 = 0.f;
  {
    int j = mrp[p], je = mrp[p+1];
    for (; j + 4 <= je; j += 4){
      int i0 = mv[j], i1 = mv[j+1], i2 = mv[j+2], i3 = mv[j+3];
      float v0 = xt[(size_t)i0*CDIM + c];
      float v1 = xt[(size_t)i1*CDIM + c];
      float v2 = xt[(size_t)i2*CDIM + c];
      float v3 = xt[(size_t)i3*CDIM + c];
      s0 += (v0 + v1) + (v2 + v3);
    }
    for (; j < je; ++j) s0 += xt[(size_t)mv[j]*CDIM + c];
  }
  float s1 = 0.f;
  {
    int j = crp[p], je = crp[p+1];
    for (; j + 4 <= je; j += 4){
      int i0 = cv[j], i1 = cv[j+1], i2 = cv[j+2], i3 = cv[j+3];
      float v0 = xt[(size_t)i0*CDIM + c];
      float v1 = xt[(size_t)i1*CDIM + c];
      float v2 = xt[(size_t)i2*CDIM + c];
      float v3 = xt[(size_t)i3*CDIM + c];
      s1 += (v0 + v1) + (v2 + v3);
    }
    for (; j < je; ++j) s1 += xt[(size_t)cv[j]*CDIM + c];
  }
  apcat[(size_t)p*384 + c]       = s0;
  apcat[(size_t)p*384 + 128 + c] = s1;
  apcat[(size_t)p*384 + 256 + c] = xp[(size_t)p*CDIM + c];
}

// ---------------- main GEMM: Out[M,128] = A[M,K] @ W[K,128] (+bias)(+epilogue)(+relu) ----------------
// block 256, tile 64 rows x 128 cols, thread: 4 cols x 8 rows
template<int K, bool EPI, bool RELU>
__global__ __launch_bounds__(256) void k_gemm(
    const float* A, int M, const float* __restrict__ W,
    const float* __restrict__ bias, float* Out,
    const float* __restrict__ yp2, const float* __restrict__ yp3,
    const int* __restrict__ mentor, const int* __restrict__ rowptr,
    const int* __restrict__ vals){
  __shared__ float As[64*36];
  __shared__ float Ws[32*128];
  const int tid  = threadIdx.x;
  const int m0   = blockIdx.x*64;
  const int c4   = (tid & 31)*4;
  const int rowg = tid >> 5;
  float4 acc[8];
  #pragma unroll
  for (int j = 0; j < 8; ++j) acc[j] = make_float4(0.f,0.f,0.f,0.f);

  for (int k0 = 0; k0 < K; k0 += 32){
    #pragma unroll
    for (int l = 0; l < 2; ++l){            // 512 float4 slots: 64 rows x 8 f4
      int q = tid + 256*l;
      int r = q >> 3, kf = q & 7;
      int row = m0 + r;
      float4 v = make_float4(0.f,0.f,0.f,0.f);
      if (row < M) v = *(const float4*)(A + (size_t)row*K + k0 + kf*4);
      *(float4*)&As[r*36 + kf*4] = v;
    }
    #pragma unroll
    for (int l = 0; l < 4; ++l){            // 1024 float4 slots: 32 k x 32 f4
      int q = tid + 256*l;
      int kk = q >> 5, cf = q & 31;
      *(float4*)&Ws[kk*128 + cf*4] = *(const float4*)(W + (size_t)(k0+kk)*128 + cf*4);
    }
    __syncthreads();
    #pragma unroll
    for (int k4 = 0; k4 < 8; ++k4){
      float4 w0 = *(const float4*)&Ws[(k4*4+0)*128 + c4];
      float4 w1 = *(const float4*)&Ws[(k4*4+1)*128 + c4];
      float4 w2 = *(const float4*)&Ws[(k4*4+2)*128 + c4];
      float4 w3 = *(const float4*)&Ws[(k4*4+3)*128 + c4];
      #pragma unroll
      for (int j = 0; j < 8; ++j){
        float4 a = *(const float4*)&As[(rowg + 8*j)*36 + k4*4];
        acc[j].x += a.x*w0.x + a.y*w1.x + a.z*w2.x + a.w*w3.x;
        acc[j].y += a.x*w0.y + a.y*w1.y + a.z*w2.y + a.w*w3.y;
        acc[j].z += a.x*w0.z + a.y*w1.z + a.z*w2.z + a.w*w3.z;
        acc[j].w += a.x*w0.w + a.y*w1.w + a.z*w2.w + a.w*w3.w;
      }
    }
    __syncthreads();
  }

  float4 bv = make_float4(0.f,0.f,0.f,0.f);
  if (bias) bv = *(const float4*)(bias + c4);
  #pragma unroll
  for (int j = 0; j < 8; ++j){
    int row = m0 + rowg + 8*j;
    if (row >= M) continue;
    float4 o = acc[j];
    o.x += bv.x; o.y += bv.y; o.z += bv.z; o.w += bv.w;
    if (EPI){
      int m = mentor[row];
      float4 y = *(const float4*)(yp2 + (size_t)m*CDIM + c4);
      o.x += y.x; o.y += y.y; o.z += y.z; o.w += y.w;
      int qb = rowptr[row], qe = rowptr[row+1];
      for (int q = qb; q < qe; ++q){
        int nb = vals[q];
        float4 y3 = *(const float4*)(yp3 + (size_t)nb*CDIM + c4);
        o.x += y3.x; o.y += y3.y; o.z += y3.z; o.w += y3.w;
      }
    }
    if (RELU){
      o.x = o.x > 0.f ? o.x : 0.f; o.y = o.y > 0.f ? o.y : 0.f;
      o.z = o.z > 0.f ? o.z : 0.f; o.w = o.w > 0.f ? o.w : 0.f;
    }
    *(float4*)(Out + (size_t)row*CDIM + c4) = o;
  }
}

// ---------------- N=32 GEMM: Out[M,32] = A[M,128] @ W[128,32] ----------------
__global__ __launch_bounds__(256) void k_gemm32(const float* __restrict__ A, int M,
                                                const float* __restrict__ W,
                                                float* __restrict__ Out){
  __shared__ float As[128*36];
  __shared__ float Ws[32*32];
  const int tid  = threadIdx.x;
  const int m0   = blockIdx.x*128;
  const int c4   = (tid & 7)*4;
  const int rowg = tid >> 3;               // 0..31
  float4 acc[4];
  #pragma unroll
  for (int j = 0; j < 4; ++j) acc[j] = make_float4(0.f,0.f,0.f,0.f);

  for (int k0 = 0; k0 < 128; k0 += 32){
    #pragma unroll
    for (int l = 0; l < 4; ++l){           // 1024 f4: 128 rows x 8 f4
      int q = tid + 256*l;
      int r = q >> 3, kf = q & 7;
      int row = m0 + r;
      float4 v = make_float4(0.f,0.f,0.f,0.f);
      if (row < M) v = *(const float4*)(A + (size_t)row*CDIM + k0 + kf*4);
      *(float4*)&As[r*36 + kf*4] = v;
    }
    {                                      // 256 f4: 32 k x 8 f4
      int kk = tid >> 3, cf = tid & 7;
      *(float4*)&Ws[kk*32 + cf*4] = *(const float4*)(W + (size_t)(k0+kk)*32 + cf*4);
    }
    __syncthreads();
    #pragma unroll
    for (int k4 = 0; k4 < 8; ++k4){
      float4 w0 = *(const float4*)&Ws[(k4*4+0)*32 + c4];
      float4 w1 = *(const float4*)&Ws[(k4*4+1)*32 + c4];
      float4 w2 = *(const float4*)&Ws[(k4*4+2)*32 + c4];
      float4 w3 = *(const float4*)&Ws[(k4*4+3)*32 + c4];
      #pragma unroll
      for (int j = 0; j < 4; ++j){
        float4 a = *(const float4*)&As[(rowg + 32*j)*36 + k4*4];
        acc[j].x += a.x*w0.x + a.y*w1.x + a.z*w2.x + a.w*w3.x;
        acc[j].y += a.x*w0.y + a.y*w1.y + a.z*w2.y + a.w*w3.y;
        acc[j].z += a.x*w0.z + a.y*w1.z + a.z*w2.z + a.w*w3.z;
        acc[j].w += a.x*w0.w + a.y*w1.w + a.z*w2.w + a.w*w3.w;
      }
    }
    __syncthreads();
  }
  #pragma unroll
  for (int j = 0; j < 4; ++j){
    int row = m0 + rowg + 32*j;
    if (row < M) *(float4*)(Out + (size_t)row*32 + c4) = acc[j];
  }
}

// ---------------- edge classifier ----------------
__global__ __launch_bounds__(256) void k_edge(
    const int* __restrict__ el0, const int* __restrict__ el1,
    const int* __restrict__ sup1,
    const float* __restrict__ zt, const float* __restrict__ zpb,
    const float* __restrict__ zpc,
    const float* __restrict__ b1, const float* __restrict__ W2,
    const float* __restrict__ b2, float* __restrict__ out, int n){
  __shared__ float sW[32], sb[32];
  if (threadIdx.x < 32){ sW[threadIdx.x] = W2[threadIdx.x]; sb[threadIdx.x] = b1[threadIdx.x]; }
  __syncthreads();
  int e = blockIdx.x*256 + threadIdx.x;
  if (e >= n) return;
  int t = el0[e], p = el1[e];
  int m = sup1[t];
  const float* zr = zt  + (size_t)t*32;
  const float* br = zpb + (size_t)m*32;
  const float* cr = zpc + (size_t)p*32;
  float acc = 0.f;
  #pragma unroll
  for (int i = 0; i < 8; ++i){
    float4 a = *(const float4*)(zr + i*4);
    float4 b = *(const float4*)(br + i*4);
    float4 c = *(const float4*)(cr + i*4);
    float h;
    h = a.x + b.x + c.x + sb[i*4+0]; h = h > 0.f ? h : 0.f; acc = fmaf(h, sW[i*4+0], acc);
    h = a.y + b.y + c.y + sb[i*4+1]; h = h > 0.f ? h : 0.f; acc = fmaf(h, sW[i*4+1], acc);
    h = a.z + b.z + c.z + sb[i*4+2]; h = h > 0.f ? h : 0.f; acc = fmaf(h, sW[i*4+2], acc);
    h = a.w + b.w + c.w + sb[i*4+3]; h = h > 0.f ? h : 0.f; acc = fmaf(h, sW[i*4+3], acc);
  }
  out[e] = acc + b2[0];
}

// ---------------- launch ----------------
extern "C" void kernel_launch(void* const* d_in, const int* in_sizes, int n_in,
                              void* d_out, int out_size, void* d_ws, size_t ws_size,
                              hipStream_t stream){
  const float* thesis_x = (const float*)d_in[0];
  const float* lin_W    = (const float*)d_in[1];
  const float* lin_b    = (const float*)d_in[2];
  const float* prof_emb = (const float*)d_in[3];
  const float* gWl      = (const float*)d_in[4];
  const float* gbl      = (const float*)d_in[5];
  const float* gWr      = (const float*)d_in[6];
  const float* cW1      = (const float*)d_in[7];
  const float* cb1      = (const float*)d_in[8];
  const float* cW2      = (const float*)d_in[9];
  const float* cb2      = (const float*)d_in[10];
  const int*   pid      = (const int*)d_in[11];
  const int*   sup0     = (const int*)d_in[12];
  const int*   sup1     = sup0 + NT;
  const int*   com0     = (const int*)d_in[13];
  const int*   com1     = com0 + EC;
  const int*   el0      = (const int*)d_in[14];
  const int*   el1      = el0 + EL;
  float* outp = (float*)d_out;

  char* base = (char*)d_ws;
  size_t off = 0;
  auto alloc = [&](size_t bytes)->void*{
    void* p = base + off;
    off += (bytes + 255) & ~(size_t)255;
    return p;
  };
  float* xt    = (float*)alloc((size_t)NT*CDIM*4);
  float* xp    = (float*)alloc((size_t)NP*CDIM*4);
  float* apcat = (float*)alloc((size_t)NP*384*4);
  float* yp2   = (float*)alloc((size_t)NP*CDIM*4);
  float* yp3   = (float*)alloc((size_t)NP*CDIM*4);
  float* Wp    = (float*)alloc((size_t)384*128*4);
  float* Wt    = (float*)alloc((size_t)128*128*4);
  float* bp    = (float*)alloc(512);
  float* bt    = (float*)alloc(512);
  float* zt    = (float*)alloc((size_t)NT*32*4);
  float* zpb   = (float*)alloc((size_t)NP*32*4);
  float* zpc   = (float*)alloc((size_t)NP*32*4);
  int* rp_t    = (int*)alloc((size_t)(NT+1)*4);
  int* v_t     = (int*)alloc((size_t)EC*4);
  int* rp_c1   = (int*)alloc((size_t)(NP+1)*4);
  int* v_c1    = (int*)alloc((size_t)EC*4);
  int* rp_m    = (int*)alloc((size_t)(NP+1)*4);
  int* v_m     = (int*)alloc((size_t)NT*4);
  int* counts  = (int*)alloc((size_t)NT*4);
  int* cursor  = (int*)alloc((size_t)NT*4);
  int* partials= (int*)alloc(4096);

  auto cdiv = [](int a, int b){ return (a + b - 1)/b; };

  auto build_csr = [&](const int* keys, const int* storev, int ne, int nb,
                       int* rowptr, int* vals){
    hipMemsetAsync(counts, 0, (size_t)nb*4, stream);
    k_hist<<<cdiv(ne,256),256,0,stream>>>(keys, ne, counts);
    int nPb = cdiv(nb,256);
    k_partial<<<nPb,256,0,stream>>>(counts, nb, partials);
    k_scan_partials<<<1,1024,0,stream>>>(partials, nPb, rowptr + nb);
    k_scan_final<<<nPb,256,0,stream>>>(counts, partials, nb, rowptr);
    k_copy_int<<<cdiv(nb,256),256,0,stream>>>(rowptr, cursor, nb);
    k_fill<<<cdiv(ne,256),256,0,stream>>>(keys, storev, ne, cursor, vals);
  };

  // CSRs: com by thesis (vals=prof), com by prof (vals=thesis), sup by prof (vals=thesis)
  build_csr(com0, com1, EC, NT, rp_t,  v_t);
  build_csr(com1, com0, EC, NP, rp_c1, v_c1);
  build_csr(sup1, sup0, NT, NP, rp_m,  v_m);

  k_xp_init<<<cdiv(NP*CDIM,256),256,0,stream>>>(prof_emb, pid, xp);

  // xt = thesis_x @ lin_W + lin_b
  k_gemm<384,false,false><<<cdiv(NT,64),256,0,stream>>>(
      thesis_x, NT, lin_W, lin_b, xt, nullptr, nullptr, nullptr, nullptr, nullptr);

  for (int l = 0; l < 2; ++l){
    k_wcombine<<<64,256,0,stream>>>(gWl, gbl, gWr, l, Wp, bp, Wt, bt);
    k_segsum<<<NP,128,0,stream>>>(xt, xp, rp_m, v_m, rp_c1, v_c1, apcat);
    // yp2 = xp @ Wl2, yp3 = xp @ Wl3 (old xp!)
    k_gemm<128,false,false><<<cdiv(NP,64),256,0,stream>>>(
        xp, NP, gWl + (size_t)(l*4+2)*16384, nullptr, yp2,
        nullptr, nullptr, nullptr, nullptr, nullptr);
    k_gemm<128,false,false><<<cdiv(NP,64),256,0,stream>>>(
        xp, NP, gWl + (size_t)(l*4+3)*16384, nullptr, yp3,
        nullptr, nullptr, nullptr, nullptr, nullptr);
    if (l == 0){
      k_gemm<384,false,true><<<cdiv(NP,64),256,0,stream>>>(
          apcat, NP, Wp, bp, xp, nullptr, nullptr, nullptr, nullptr, nullptr);
      k_gemm<128,true,true><<<cdiv(NT,64),256,0,stream>>>(
          xt, NT, Wt, bt, xt, yp2, yp3, sup1, rp_t, v_t);
    } else {
      k_gemm<384,false,false><<<cdiv(NP,64),256,0,stream>>>(
          apcat, NP, Wp, bp, xp, nullptr, nullptr, nullptr, nullptr, nullptr);
      k_gemm<128,true,false><<<cdiv(NT,64),256,0,stream>>>(
          xt, NT, Wt, bt, xt, yp2, yp3, sup1, rp_t, v_t);
    }
  }

  // classifier precomputes
  k_gemm32<<<cdiv(NT,128),256,0,stream>>>(xt, NT, cW1,            zt);
  k_gemm32<<<cdiv(NP,128),256,0,stream>>>(xp, NP, cW1 + 128*32,   zpb);
  k_gemm32<<<cdiv(NP,128),256,0,stream>>>(xp, NP, cW1 + 256*32,   zpc);
  k_edge<<<cdiv(EL,256),256,0,stream>>>(el0, el1, sup1, zt, zpb, zpc,
                                        cb1, cW2, cb2, outp, EL);
}

// Round 2
// 1358.935 us; speedup vs baseline: 1.7234x; 1.7234x over previous
//
#include <hip/hip_runtime.h>
#include <hip/hip_bf16.h>
#include <cstdint>
#include <cstddef>

#define NT 200000
#define NP 5000
#define FDIM 384
#define CDIM 128
#define EC 600000
#define EL 400000

typedef unsigned int uint;
typedef unsigned short ushort;
typedef __attribute__((ext_vector_type(8))) __bf16 bf16x8;
typedef __attribute__((ext_vector_type(4))) float f32x4;

union FragU { uint4 u; bf16x8 b; };

__device__ __forceinline__ ushort f2bf(float f){
  uint u = __float_as_uint(f);
  u = (u + 0x7fffu + ((u >> 16) & 1u)) >> 16;
  return (ushort)u;
}
__device__ __forceinline__ float bf2f(ushort h){
  return __uint_as_float(((uint)h) << 16);
}

// ---------------- CSR build (counting sort) ----------------
__global__ void k_hist(const int* __restrict__ keys, int n, int* __restrict__ counts){
  int i = blockIdx.x*256 + threadIdx.x;
  if (i < n) atomicAdd(&counts[keys[i]], 1);
}

__global__ void k_partial(const int* __restrict__ counts, int n, int* __restrict__ partials){
  __shared__ int s[256];
  int i = blockIdx.x*256 + threadIdx.x;
  s[threadIdx.x] = (i < n) ? counts[i] : 0;
  __syncthreads();
  for (int off = 128; off > 0; off >>= 1){
    if (threadIdx.x < off) s[threadIdx.x] += s[threadIdx.x + off];
    __syncthreads();
  }
  if (threadIdx.x == 0) partials[blockIdx.x] = s[0];
}

__global__ void k_scan_partials(int* __restrict__ partials, int nP, int* __restrict__ total_out){
  __shared__ int s[1024];
  int carry = 0;
  for (int base = 0; base < nP; base += 1024){
    int i = base + threadIdx.x;
    int v = (i < nP) ? partials[i] : 0;
    s[threadIdx.x] = v; __syncthreads();
    for (int off = 1; off < 1024; off <<= 1){
      int t = (threadIdx.x >= off) ? s[threadIdx.x - off] : 0;
      __syncthreads();
      s[threadIdx.x] += t;
      __syncthreads();
    }
    if (i < nP) partials[i] = carry + s[threadIdx.x] - v;  // exclusive
    int chunk_total = s[1023];
    __syncthreads();
    carry += chunk_total;
  }
  if (threadIdx.x == 0 && total_out) *total_out = carry;
}

__global__ void k_scan_final(const int* __restrict__ counts, const int* __restrict__ pscan,
                             int n, int* __restrict__ rowptr){
  __shared__ int s[256];
  int tid = threadIdx.x;
  int i = blockIdx.x*256 + tid;
  int v = (i < n) ? counts[i] : 0;
  s[tid] = v; __syncthreads();
  for (int off = 1; off < 256; off <<= 1){
    int t = (tid >= off) ? s[tid - off] : 0;
    __syncthreads();
    s[tid] += t;
    __syncthreads();
  }
  if (i < n) rowptr[i] = pscan[blockIdx.x] + s[tid] - v;
}

__global__ void k_copy_int(const int* __restrict__ src, int* __restrict__ dst, int n){
  int i = blockIdx.x*256 + threadIdx.x;
  if (i < n) dst[i] = src[i];
}

__global__ void k_fill(const int* __restrict__ keys, const int* __restrict__ storev,
                       int n, int* __restrict__ cursor, int* __restrict__ vals){
  int e = blockIdx.x*256 + threadIdx.x;
  if (e < n){
    int k = keys[e];
    int pos = atomicAdd(&cursor[k], 1);
    vals[pos] = storev ? storev[e] : e;
  }
}

// ---------------- xp init ----------------
__global__ void k_xp_init(const float* __restrict__ pe, const int* __restrict__ pid,
                          float* __restrict__ xp){
  int i = blockIdx.x*256 + threadIdx.x;
  if (i < NP*CDIM){
    int p = i >> 7, c = i & 127;
    xp[i] = pe[(size_t)pid[p]*CDIM + c];
  }
}

// ---------------- weight combine per layer ----------------
__global__ void k_wcombine(const float* __restrict__ gWl, const float* __restrict__ gbl,
                           const float* __restrict__ gWr, int layer,
                           float* __restrict__ Wp, float* __restrict__ bp,
                           float* __restrict__ Wt, float* __restrict__ bt){
  int i = blockIdx.x*256 + threadIdx.x;
  const float* Wl_l = gWl + (size_t)layer*4*16384;
  const float* Wr_l = gWr + (size_t)layer*4*16384;
  const float* bl_l = gbl + (size_t)layer*4*128;
  if (i < 16384){
    Wp[i]          = Wl_l[i];
    Wp[16384 + i]  = Wl_l[16384 + i];
    Wp[32768 + i]  = Wr_l[i] + Wr_l[16384 + i];
    Wt[i]          = Wr_l[2*16384 + i] + Wr_l[3*16384 + i];
  }
  if (i < 128){
    bp[i] = bl_l[i] + bl_l[128 + i];
    bt[i] = bl_l[2*128 + i] + bl_l[3*128 + i];
  }
}

// ---------------- pack W[K][N] fp32 row-major into MFMA B-fragment order, bf16 ----------------
// slot layout: [kc = k/32][nt = n/16][lane = (kwithin/8)*16 + (n&15)][j = k&7]
__global__ void k_packW(const float* __restrict__ W, ushort* __restrict__ out, int K, int N){
  int o = blockIdx.x*256 + threadIdx.x;
  if (o >= K*N) return;
  int j   = o & 7;
  int lane = (o >> 3) & 63;
  int q   = lane >> 4, nl = lane & 15;
  int tl  = o >> 9;
  int nt  = tl % (N >> 4);
  int kc  = tl / (N >> 4);
  int k   = kc*32 + q*8 + j;
  int n   = nt*16 + nl;
  out[o] = f2bf(W[(size_t)k*N + n]);
}

// ---------------- segment sums into apcat = [a0 | a1 | xp] (NP x 384), xt in bf16 ----------------
__global__ __launch_bounds__(128) void k_segsum(
    const ushort* __restrict__ xt, const float* __restrict__ xp,
    const int* __restrict__ mrp, const int* __restrict__ mv,
    const int* __restrict__ crp, const int* __restrict__ cv,
    float* __restrict__ apcat){
  int p = blockIdx.x, c = threadIdx.x;
  float s0 = 0.f;
  {
    int j = mrp[p], je = mrp[p+1];
    for (; j + 4 <= je; j += 4){
      int i0 = mv[j], i1 = mv[j+1], i2 = mv[j+2], i3 = mv[j+3];
      float v0 = bf2f(xt[(size_t)i0*CDIM + c]);
      float v1 = bf2f(xt[(size_t)i1*CDIM + c]);
      float v2 = bf2f(xt[(size_t)i2*CDIM + c]);
      float v3 = bf2f(xt[(size_t)i3*CDIM + c]);
      s0 += (v0 + v1) + (v2 + v3);
    }
    for (; j < je; ++j) s0 += bf2f(xt[(size_t)mv[j]*CDIM + c]);
  }
  float s1 = 0.f;
  {
    int j = crp[p], je = crp[p+1];
    for (; j + 4 <= je; j += 4){
      int i0 = cv[j], i1 = cv[j+1], i2 = cv[j+2], i3 = cv[j+3];
      float v0 = bf2f(xt[(size_t)i0*CDIM + c]);
      float v1 = bf2f(xt[(size_t)i1*CDIM + c]);
      float v2 = bf2f(xt[(size_t)i2*CDIM + c]);
      float v3 = bf2f(xt[(size_t)i3*CDIM + c]);
      s1 += (v0 + v1) + (v2 + v3);
    }
    for (; j < je; ++j) s1 += bf2f(xt[(size_t)cv[j]*CDIM + c]);
  }
  apcat[(size_t)p*384 + c]       = s0;
  apcat[(size_t)p*384 + 128 + c] = s1;
  apcat[(size_t)p*384 + 256 + c] = xp[(size_t)p*CDIM + c];
}

// ---------------- MFMA GEMM: Outbf[M,128] = bf16( A[M,K]@W + bias (+EPI) (+relu) ) --------------
// 256 thr = 4 waves in 2x2; wave computes 64x64 via 4x4 grid of 16x16x32 MFMA. BK=32.
// A fp32 (AF32) or bf16; W pre-packed fragment order bf16.
template<int K, bool AF32, bool EPI, bool RELU>
__global__ __launch_bounds__(256) void k_mm(
    const void* __restrict__ Ain, int M,
    const ushort* __restrict__ Wfrag, const float* __restrict__ bias,
    ushort* __restrict__ Outbf,
    const float* __restrict__ yp2, const float* __restrict__ yp3,
    const int* __restrict__ mentor, const int* __restrict__ rowptr,
    const int* __restrict__ vals){
  __shared__ uint4 As[512];   // [rt 0..7][lane 0..63] 16B
  __shared__ uint4 Bs[512];   // [nt 0..7][lane 0..63] 16B
  const int tid  = threadIdx.x;
  const int lane = tid & 63;
  const int wave = tid >> 6;
  const int wr   = wave >> 1, wc = wave & 1;
  const int m0   = blockIdx.x * 128;
  const float* Af = (const float*)Ain;
  const ushort* Ab = (const ushort*)Ain;

  f32x4 acc[4][4];
  #pragma unroll
  for (int i = 0; i < 4; ++i)
    #pragma unroll
    for (int j = 0; j < 4; ++j) acc[i][j] = (f32x4)(0.f);

  const int rs = tid >> 2;   // staging row 0..63
  const int qs = tid & 3;    // staging k-octet 0..3

  for (int kc = 0; kc < K/32; ++kc){
    // --- stage A: 128 rows x 32 k, frag order ---
    #pragma unroll
    for (int h = 0; h < 2; ++h){
      int rr = rs + 64*h;
      int grow = m0 + rr;
      uint4 payload = make_uint4(0,0,0,0);
      if (grow < M){
        if (AF32){
          const float* ap = Af + (size_t)grow*K + kc*32 + qs*8;
          float4 fa = *(const float4*)ap;
          float4 fb = *(const float4*)(ap + 4);
          payload.x = (uint)f2bf(fa.x) | ((uint)f2bf(fa.y) << 16);
          payload.y = (uint)f2bf(fa.z) | ((uint)f2bf(fa.w) << 16);
          payload.z = (uint)f2bf(fb.x) | ((uint)f2bf(fb.y) << 16);
          payload.w = (uint)f2bf(fb.z) | ((uint)f2bf(fb.w) << 16);
        } else {
          payload = *(const uint4*)(Ab + (size_t)grow*K + kc*32 + qs*8);
        }
      }
      As[(rr >> 4)*64 + qs*16 + (rr & 15)] = payload;
    }
    // --- stage B: sequential copy of packed chunk (512 x 16B) ---
    const uint4* wsrc = (const uint4*)Wfrag + (size_t)kc*512;
    Bs[tid]       = wsrc[tid];
    Bs[tid + 256] = wsrc[tid + 256];
    __syncthreads();

    bf16x8 a[4], b[4];
    #pragma unroll
    for (int i = 0; i < 4; ++i){ FragU u; u.u = As[(wr*4 + i)*64 + lane]; a[i] = u.b; }
    #pragma unroll
    for (int j = 0; j < 4; ++j){ FragU u; u.u = Bs[(wc*4 + j)*64 + lane]; b[j] = u.b; }
    #pragma unroll
    for (int i = 0; i < 4; ++i)
      #pragma unroll
      for (int j = 0; j < 4; ++j)
        acc[i][j] = __builtin_amdgcn_mfma_f32_16x16x32_bf16(a[i], b[j], acc[i][j], 0, 0, 0);
    __syncthreads();
  }

  // --- epilogue ---
  const int colb = wc*64 + (lane & 15);        // + j*16
  float bv[4];
  #pragma unroll
  for (int j = 0; j < 4; ++j) bv[j] = bias ? bias[colb + j*16] : 0.f;

  #pragma unroll
  for (int i = 0; i < 4; ++i){
    int r0 = m0 + wr*64 + i*16 + (lane >> 4)*4;
    #pragma unroll
    for (int reg = 0; reg < 4; ++reg){
      int row = r0 + reg;
      if (row >= M) continue;
      float s0 = bv[0], s1 = bv[1], s2 = bv[2], s3 = bv[3];
      if (EPI){
        int m = mentor[row];
        const float* y2 = yp2 + (size_t)m*CDIM + colb;
        s0 += y2[0]; s1 += y2[16]; s2 += y2[32]; s3 += y2[48];
        int qb = rowptr[row], qe = rowptr[row+1];
        for (int q = qb; q < qe; ++q){
          const float* y3 = yp3 + (size_t)vals[q]*CDIM + colb;
          s0 += y3[0]; s1 += y3[16]; s2 += y3[32]; s3 += y3[48];
        }
      }
      float v0 = acc[i][0][reg] + s0;
      float v1 = acc[i][1][reg] + s1;
      float v2 = acc[i][2][reg] + s2;
      float v3 = acc[i][3][reg] + s3;
      if (RELU){
        v0 = v0 > 0.f ? v0 : 0.f; v1 = v1 > 0.f ? v1 : 0.f;
        v2 = v2 > 0.f ? v2 : 0.f; v3 = v3 > 0.f ? v3 : 0.f;
      }
      ushort* orow = Outbf + (size_t)row*CDIM + colb;
      orow[0]  = f2bf(v0); orow[16] = f2bf(v1);
      orow[32] = f2bf(v2); orow[48] = f2bf(v3);
    }
  }
}

// ---------------- MFMA GEMM N=32: zt[M,32] fp32 = Abf[M,128] @ Wfrag(128x32) ----------------
__global__ __launch_bounds__(256) void k_mm_n32(
    const ushort* __restrict__ Ab, int M,
    const ushort* __restrict__ Wfrag, float* __restrict__ Out){
  __shared__ uint4 As[512];   // [rt 0..7][lane] per 32-k chunk
  __shared__ uint4 Bs[512];   // all 4 chunks x 2 nt x 64 lanes
  const int tid  = threadIdx.x;
  const int lane = tid & 63;
  const int w    = tid >> 6;
  const int m0   = blockIdx.x * 128;

  Bs[tid]       = ((const uint4*)Wfrag)[tid];
  Bs[tid + 256] = ((const uint4*)Wfrag)[tid + 256];

  f32x4 acc[2][2];
  #pragma unroll
  for (int i = 0; i < 2; ++i)
    #pragma unroll
    for (int j = 0; j < 2; ++j) acc[i][j] = (f32x4)(0.f);

  const int rs = tid >> 2, qs = tid & 3;
  for (int kc = 0; kc < 4; ++kc){
    #pragma unroll
    for (int h = 0; h < 2; ++h){
      int rr = rs + 64*h;
      int grow = m0 + rr;
      uint4 payload = make_uint4(0,0,0,0);
      if (grow < M)
        payload = *(const uint4*)(Ab + (size_t)grow*CDIM + kc*32 + qs*8);
      As[(rr >> 4)*64 + qs*16 + (rr & 15)] = payload;
    }
    __syncthreads();
    bf16x8 a[2], b[2];
    #pragma unroll
    for (int i = 0; i < 2; ++i){ FragU u; u.u = As[(w*2 + i)*64 + lane]; a[i] = u.b; }
    #pragma unroll
    for (int j = 0; j < 2; ++j){ FragU u; u.u = Bs[(kc*2 + j)*64 + lane]; b[j] = u.b; }
    #pragma unroll
    for (int i = 0; i < 2; ++i)
      #pragma unroll
      for (int j = 0; j < 2; ++j)
        acc[i][j] = __builtin_amdgcn_mfma_f32_16x16x32_bf16(a[i], b[j], acc[i][j], 0, 0, 0);
    __syncthreads();
  }

  #pragma unroll
  for (int i = 0; i < 2; ++i){
    int r0 = m0 + w*32 + i*16 + (lane >> 4)*4;
    #pragma unroll
    for (int reg = 0; reg < 4; ++reg){
      int row = r0 + reg;
      if (row >= M) continue;
      float* orow = Out + (size_t)row*32 + (lane & 15);
      orow[0]  = acc[i][0][reg];
      orow[16] = acc[i][1][reg];
    }
  }
}

// ---------------- fp32 GEMM (prof-side, small M) ----------------
template<int K, bool EPI, bool RELU>
__global__ __launch_bounds__(256) void k_gemm(
    const float* A, int M, const float* __restrict__ W,
    const float* __restrict__ bias, float* Out,
    const float* __restrict__ yp2, const float* __restrict__ yp3,
    const int* __restrict__ mentor, const int* __restrict__ rowptr,
    const int* __restrict__ vals){
  __shared__ float As[64*36];
  __shared__ float Ws[32*128];
  const int tid  = threadIdx.x;
  const int m0   = blockIdx.x*64;
  const int c4   = (tid & 31)*4;
  const int rowg = tid >> 5;
  float4 acc[8];
  #pragma unroll
  for (int j = 0; j < 8; ++j) acc[j] = make_float4(0.f,0.f,0.f,0.f);

  for (int k0 = 0; k0 < K; k0 += 32){
    #pragma unroll
    for (int l = 0; l < 2; ++l){
      int q = tid + 256*l;
      int r = q >> 3, kf = q & 7;
      int row = m0 + r;
      float4 v = make_float4(0.f,0.f,0.f,0.f);
      if (row < M) v = *(const float4*)(A + (size_t)row*K + k0 + kf*4);
      *(float4*)&As[r*36 + kf*4] = v;
    }
    #pragma unroll
    for (int l = 0; l < 4; ++l){
      int q = tid + 256*l;
      int kk = q >> 5, cf = q & 31;
      *(float4*)&Ws[kk*128 + cf*4] = *(const float4*)(W + (size_t)(k0+kk)*128 + cf*4);
    }
    __syncthreads();
    #pragma unroll
    for (int k4 = 0; k4 < 8; ++k4){
      float4 w0 = *(const float4*)&Ws[(k4*4+0)*128 + c4];
      float4 w1 = *(const float4*)&Ws[(k4*4+1)*128 + c4];
      float4 w2 = *(const float4*)&Ws[(k4*4+2)*128 + c4];
      float4 w3 = *(const float4*)&Ws[(k4*4+3)*128 + c4];
      #pragma unroll
      for (int j = 0; j < 8; ++j){
        float4 a = *(const float4*)&As[(rowg + 8*j)*36 + k4*4];
        acc[j].x += a.x*w0.x + a.y*w1.x + a.z*w2.x + a.w*w3.x;
        acc[j].y += a.x*w0.y + a.y*w1.y + a.z*w2.y + a.w*w3.y;
        acc[j].z += a.x*w0.z + a.y*w1.z + a.z*w2.z + a.w*w3.z;
        acc[j].w += a.x*w0.w + a.y*w1.w + a.z*w2.w + a.w*w3.w;
      }
    }
    __syncthreads();
  }

  float4 bv = make_float4(0.f,0.f,0.f,0.f);
  if (bias) bv = *(const float4*)(bias + c4);
  #pragma unroll
  for (int j = 0; j < 8; ++j){
    int row = m0 + rowg + 8*j;
    if (row >= M) continue;
    float4 o = acc[j];
    o.x += bv.x; o.y += bv.y; o.z += bv.z; o.w += bv.w;
    if (RELU){
      o.x = o.x > 0.f ? o.x : 0.f; o.y = o.y > 0.f ? o.y : 0.f;
      o.z = o.z > 0.f ? o.z : 0.f; o.w = o.w > 0.f ? o.w : 0.f;
    }
    *(float4*)(Out + (size_t)row*CDIM + c4) = o;
  }
}

// ---------------- N=32 fp32 GEMM (prof-side zpb/zpc) ----------------
__global__ __launch_bounds__(256) void k_gemm32(const float* __restrict__ A, int M,
                                                const float* __restrict__ W,
                                                float* __restrict__ Out){
  __shared__ float As[128*36];
  __shared__ float Ws[32*32];
  const int tid  = threadIdx.x;
  const int m0   = blockIdx.x*128;
  const int c4   = (tid & 7)*4;
  const int rowg = tid >> 3;
  float4 acc[4];
  #pragma unroll
  for (int j = 0; j < 4; ++j) acc[j] = make_float4(0.f,0.f,0.f,0.f);

  for (int k0 = 0; k0 < 128; k0 += 32){
    #pragma unroll
    for (int l = 0; l < 4; ++l){
      int q = tid + 256*l;
      int r = q >> 3, kf = q & 7;
      int row = m0 + r;
      float4 v = make_float4(0.f,0.f,0.f,0.f);
      if (row < M) v = *(const float4*)(A + (size_t)row*CDIM + k0 + kf*4);
      *(float4*)&As[r*36 + kf*4] = v;
    }
    {
      int kk = tid >> 3, cf = tid & 7;
      *(float4*)&Ws[kk*32 + cf*4] = *(const float4*)(W + (size_t)(k0+kk)*32 + cf*4);
    }
    __syncthreads();
    #pragma unroll
    for (int k4 = 0; k4 < 8; ++k4){
      float4 w0 = *(const float4*)&Ws[(k4*4+0)*32 + c4];
      float4 w1 = *(const float4*)&Ws[(k4*4+1)*32 + c4];
      float4 w2 = *(const float4*)&Ws[(k4*4+2)*32 + c4];
      float4 w3 = *(const float4*)&Ws[(k4*4+3)*32 + c4];
      #pragma unroll
      for (int j = 0; j < 4; ++j){
        float4 a = *(const float4*)&As[(rowg + 32*j)*36 + k4*4];
        acc[j].x += a.x*w0.x + a.y*w1.x + a.z*w2.x + a.w*w3.x;
        acc[j].y += a.x*w0.y + a.y*w1.y + a.z*w2.y + a.w*w3.y;
        acc[j].z += a.x*w0.z + a.y*w1.z + a.z*w2.z + a.w*w3.z;
        acc[j].w += a.x*w0.w + a.y*w1.w + a.z*w2.w + a.w*w3.w;
      }
    }
    __syncthreads();
  }
  #pragma unroll
  for (int j = 0; j < 4; ++j){
    int row = m0 + rowg + 32*j;
    if (row < M) *(float4*)(Out + (size_t)row*32 + c4) = acc[j];
  }
}

// ---------------- edge classifier ----------------
__global__ __launch_bounds__(256) void k_edge(
    const int* __restrict__ el0, const int* __restrict__ el1,
    const int* __restrict__ sup1,
    const float* __restrict__ zt, const float* __restrict__ zpb,
    const float* __restrict__ zpc,
    const float* __restrict__ b1, const float* __restrict__ W2,
    const float* __restrict__ b2, float* __restrict__ out, int n){
  __shared__ float sW[32], sb[32];
  if (threadIdx.x < 32){ sW[threadIdx.x] = W2[threadIdx.x]; sb[threadIdx.x] = b1[threadIdx.x]; }
  __syncthreads();
  int e = blockIdx.x*256 + threadIdx.x;
  if (e >= n) return;
  int t = el0[e], p = el1[e];
  int m = sup1[t];
  const float* zr = zt  + (size_t)t*32;
  const float* br = zpb + (size_t)m*32;
  const float* cr = zpc + (size_t)p*32;
  float acc = 0.f;
  #pragma unroll
  for (int i = 0; i < 8; ++i){
    float4 a = *(const float4*)(zr + i*4);
    float4 b = *(const float4*)(br + i*4);
    float4 c = *(const float4*)(cr + i*4);
    float h;
    h = a.x + b.x + c.x + sb[i*4+0]; h = h > 0.f ? h : 0.f; acc = fmaf(h, sW[i*4+0], acc);
    h = a.y + b.y + c.y + sb[i*4+1]; h = h > 0.f ? h : 0.f; acc = fmaf(h, sW[i*4+1], acc);
    h = a.z + b.z + c.z + sb[i*4+2]; h = h > 0.f ? h : 0.f; acc = fmaf(h, sW[i*4+2], acc);
    h = a.w + b.w + c.w + sb[i*4+3]; h = h > 0.f ? h : 0.f; acc = fmaf(h, sW[i*4+3], acc);
  }
  out[e] = acc + b2[0];
}

// ---------------- launch ----------------
extern "C" void kernel_launch(void* const* d_in, const int* in_sizes, int n_in,
                              void* d_out, int out_size, void* d_ws, size_t ws_size,
                              hipStream_t stream){
  const float* thesis_x = (const float*)d_in[0];
  const float* lin_W    = (const float*)d_in[1];
  const float* lin_b    = (const float*)d_in[2];
  const float* prof_emb = (const float*)d_in[3];
  const float* gWl      = (const float*)d_in[4];
  const float* gbl      = (const float*)d_in[5];
  const float* gWr      = (const float*)d_in[6];
  const float* cW1      = (const float*)d_in[7];
  const float* cb1      = (const float*)d_in[8];
  const float* cW2      = (const float*)d_in[9];
  const float* cb2      = (const float*)d_in[10];
  const int*   pid      = (const int*)d_in[11];
  const int*   sup0     = (const int*)d_in[12];
  const int*   sup1     = sup0 + NT;
  const int*   com0     = (const int*)d_in[13];
  const int*   com1     = com0 + EC;
  const int*   el0      = (const int*)d_in[14];
  const int*   el1      = el0 + EL;
  float* outp = (float*)d_out;

  char* base = (char*)d_ws;
  size_t off = 0;
  auto alloc = [&](size_t bytes)->void*{
    void* p = base + off;
    off += (bytes + 255) & ~(size_t)255;
    return p;
  };
  ushort* xt     = (ushort*)alloc((size_t)NT*CDIM*2);     // bf16 activations
  float*  xp     = (float*)alloc((size_t)NP*CDIM*4);
  float*  apcat  = (float*)alloc((size_t)NP*384*4);
  float*  yp2    = (float*)alloc((size_t)NP*CDIM*4);
  float*  yp3    = (float*)alloc((size_t)NP*CDIM*4);
  float*  Wp     = (float*)alloc((size_t)384*128*4);
  float*  Wt     = (float*)alloc((size_t)128*128*4);
  float*  bp     = (float*)alloc(512);
  float*  bt     = (float*)alloc(512);
  ushort* WmFrag = (ushort*)alloc((size_t)384*128*2);
  ushort* WtFrag = (ushort*)alloc((size_t)128*128*2);
  ushort* W1aFrag= (ushort*)alloc((size_t)128*32*2);
  float*  zt     = (float*)alloc((size_t)NT*32*4);
  float*  zpb    = (float*)alloc((size_t)NP*32*4);
  float*  zpc    = (float*)alloc((size_t)NP*32*4);
  int* rp_t    = (int*)alloc((size_t)(NT+1)*4);
  int* v_t     = (int*)alloc((size_t)EC*4);
  int* rp_c1   = (int*)alloc((size_t)(NP+1)*4);
  int* v_c1    = (int*)alloc((size_t)EC*4);
  int* rp_m    = (int*)alloc((size_t)(NP+1)*4);
  int* v_m     = (int*)alloc((size_t)NT*4);
  int* counts  = (int*)alloc((size_t)NT*4);
  int* cursor  = (int*)alloc((size_t)NT*4);
  int* partials= (int*)alloc(4096);

  auto cdiv = [](int a, int b){ return (a + b - 1)/b; };

  auto build_csr = [&](const int* keys, const int* storev, int ne, int nb,
                       int* rowptr, int* vals){
    hipMemsetAsync(counts, 0, (size_t)nb*4, stream);
    k_hist<<<cdiv(ne,256),256,0,stream>>>(keys, ne, counts);
    int nPb = cdiv(nb,256);
    k_partial<<<nPb,256,0,stream>>>(counts, nb, partials);
    k_scan_partials<<<1,1024,0,stream>>>(partials, nPb, rowptr + nb);
    k_scan_final<<<nPb,256,0,stream>>>(counts, partials, nb, rowptr);
    k_copy_int<<<cdiv(nb,256),256,0,stream>>>(rowptr, cursor, nb);
    k_fill<<<cdiv(ne,256),256,0,stream>>>(keys, storev, ne, cursor, vals);
  };

  build_csr(com0, com1, EC, NT, rp_t,  v_t);
  build_csr(com1, com0, EC, NP, rp_c1, v_c1);
  build_csr(sup1, sup0, NT, NP, rp_m,  v_m);

  k_xp_init<<<cdiv(NP*CDIM,256),256,0,stream>>>(prof_emb, pid, xp);

  // pack main weight; xt = bf16(thesis_x @ lin_W + lin_b)
  k_packW<<<cdiv(384*128,256),256,0,stream>>>(lin_W, WmFrag, 384, 128);
  k_mm<384,true,false,false><<<cdiv(NT,128),256,0,stream>>>(
      thesis_x, NT, WmFrag, lin_b, xt, nullptr, nullptr, nullptr, nullptr, nullptr);

  for (int l = 0; l < 2; ++l){
    k_wcombine<<<64,256,0,stream>>>(gWl, gbl, gWr, l, Wp, bp, Wt, bt);
    k_packW<<<cdiv(128*128,256),256,0,stream>>>(Wt, WtFrag, 128, 128);
    k_segsum<<<NP,128,0,stream>>>(xt, xp, rp_m, v_m, rp_c1, v_c1, apcat);
    // yp2 = xp @ Wl2, yp3 = xp @ Wl3 (old xp)
    k_gemm<128,false,false><<<cdiv(NP,64),256,0,stream>>>(
        xp, NP, gWl + (size_t)(l*4+2)*16384, nullptr, yp2,
        nullptr, nullptr, nullptr, nullptr, nullptr);
    k_gemm<128,false,false><<<cdiv(NP,64),256,0,stream>>>(
        xp, NP, gWl + (size_t)(l*4+3)*16384, nullptr, yp3,
        nullptr, nullptr, nullptr, nullptr, nullptr);
    if (l == 0){
      k_gemm<384,false,true><<<cdiv(NP,64),256,0,stream>>>(
          apcat, NP, Wp, bp, xp, nullptr, nullptr, nullptr, nullptr, nullptr);
      k_mm<128,false,true,true><<<cdiv(NT,128),256,0,stream>>>(
          xt, NT, WtFrag, bt, xt, yp2, yp3, sup1, rp_t, v_t);
    } else {
      k_gemm<384,false,false><<<cdiv(NP,64),256,0,stream>>>(
          apcat, NP, Wp, bp, xp, nullptr, nullptr, nullptr, nullptr, nullptr);
      k_mm<128,false,true,false><<<cdiv(NT,128),256,0,stream>>>(
          xt, NT, WtFrag, bt, xt, yp2, yp3, sup1, rp_t, v_t);
    }
  }

  // classifier precomputes
  k_packW<<<cdiv(128*32,256),256,0,stream>>>(cW1, W1aFrag, 128, 32);
  k_mm_n32<<<cdiv(NT,128),256,0,stream>>>(xt, NT, W1aFrag, zt);
  k_gemm32<<<cdiv(NP,128),256,0,stream>>>(xp, NP, cW1 + 128*32, zpb);
  k_gemm32<<<cdiv(NP,128),256,0,stream>>>(xp, NP, cW1 + 256*32, zpc);
  k_edge<<<cdiv(EL,256),256,0,stream>>>(el0, el1, sup1, zt, zpb, zpc,
                                        cb1, cW2, cb2, outp, EL);
}

// Round 3
// 1129.687 us; speedup vs baseline: 2.0731x; 1.2029x over previous
//
#include <hip/hip_runtime.h>
#include <hip/hip_bf16.h>
#include <cstdint>
#include <cstddef>

#define NT 200000
#define NP 5000
#define FDIM 384
#define CDIM 128
#define EC 600000
#define EL 400000

typedef unsigned int uint;
typedef unsigned short ushort;
typedef __attribute__((ext_vector_type(8))) __bf16 bf16x8;
typedef __attribute__((ext_vector_type(4))) float f32x4;

union FragU { uint4 u; bf16x8 b; };

__device__ __forceinline__ ushort f2bf(float f){
  uint u = __float_as_uint(f);
  u = (u + 0x7fffu + ((u >> 16) & 1u)) >> 16;
  return (ushort)u;
}
__device__ __forceinline__ float bf2f(ushort h){
  return __uint_as_float(((uint)h) << 16);
}

// ---------------- CSR build (counting sort) ----------------
__global__ void k_hist(const int* __restrict__ keys, int n, int* __restrict__ counts){
  int i = blockIdx.x*256 + threadIdx.x;
  if (i < n) atomicAdd(&counts[keys[i]], 1);
}

__global__ void k_partial(const int* __restrict__ counts, int n, int* __restrict__ partials){
  __shared__ int s[256];
  int i = blockIdx.x*256 + threadIdx.x;
  s[threadIdx.x] = (i < n) ? counts[i] : 0;
  __syncthreads();
  for (int off = 128; off > 0; off >>= 1){
    if (threadIdx.x < off) s[threadIdx.x] += s[threadIdx.x + off];
    __syncthreads();
  }
  if (threadIdx.x == 0) partials[blockIdx.x] = s[0];
}

__global__ void k_scan_partials(int* __restrict__ partials, int nP, int* __restrict__ total_out){
  __shared__ int s[1024];
  int carry = 0;
  for (int base = 0; base < nP; base += 1024){
    int i = base + threadIdx.x;
    int v = (i < nP) ? partials[i] : 0;
    s[threadIdx.x] = v; __syncthreads();
    for (int off = 1; off < 1024; off <<= 1){
      int t = (threadIdx.x >= off) ? s[threadIdx.x - off] : 0;
      __syncthreads();
      s[threadIdx.x] += t;
      __syncthreads();
    }
    if (i < nP) partials[i] = carry + s[threadIdx.x] - v;  // exclusive
    int chunk_total = s[1023];
    __syncthreads();
    carry += chunk_total;
  }
  if (threadIdx.x == 0 && total_out) *total_out = carry;
}

__global__ void k_scan_final(const int* __restrict__ counts, const int* __restrict__ pscan,
                             int n, int* __restrict__ rowptr){
  __shared__ int s[256];
  int tid = threadIdx.x;
  int i = blockIdx.x*256 + tid;
  int v = (i < n) ? counts[i] : 0;
  s[tid] = v; __syncthreads();
  for (int off = 1; off < 256; off <<= 1){
    int t = (tid >= off) ? s[tid - off] : 0;
    __syncthreads();
    s[tid] += t;
    __syncthreads();
  }
  if (i < n) rowptr[i] = pscan[blockIdx.x] + s[tid] - v;
}

__global__ void k_copy_int(const int* __restrict__ src, int* __restrict__ dst, int n){
  int i = blockIdx.x*256 + threadIdx.x;
  if (i < n) dst[i] = src[i];
}

__global__ void k_fill(const int* __restrict__ keys, const int* __restrict__ storev,
                       int n, int* __restrict__ cursor, int* __restrict__ vals){
  int e = blockIdx.x*256 + threadIdx.x;
  if (e < n){
    int k = keys[e];
    int pos = atomicAdd(&cursor[k], 1);
    vals[pos] = storev ? storev[e] : e;
  }
}

// ---------------- xp init ----------------
__global__ void k_xp_init(const float* __restrict__ pe, const int* __restrict__ pid,
                          float* __restrict__ xp){
  int i = blockIdx.x*256 + threadIdx.x;
  if (i < NP*CDIM){
    int p = i >> 7, c = i & 127;
    xp[i] = pe[(size_t)pid[p]*CDIM + c];
  }
}

// ---------------- weight combine per layer ----------------
// Wp [384,128] = [Wl0 ; Wl1 ; Wr0+Wr1], bp = bl0+bl1
// Wt [128,128] = Wr2+Wr3, btp = perm(bl2+bl3)
__global__ void k_wcombine(const float* __restrict__ gWl, const float* __restrict__ gbl,
                           const float* __restrict__ gWr, int layer,
                           float* __restrict__ Wp, float* __restrict__ bp,
                           float* __restrict__ Wt, float* __restrict__ btp){
  int i = blockIdx.x*256 + threadIdx.x;
  const float* Wl_l = gWl + (size_t)layer*4*16384;
  const float* Wr_l = gWr + (size_t)layer*4*16384;
  const float* bl_l = gbl + (size_t)layer*4*128;
  if (i < 16384){
    Wp[i]          = Wl_l[i];
    Wp[16384 + i]  = Wl_l[16384 + i];
    Wp[32768 + i]  = Wr_l[i] + Wr_l[16384 + i];
    Wt[i]          = Wr_l[2*16384 + i] + Wr_l[3*16384 + i];
  }
  if (i < 128){
    bp[i] = bl_l[i] + bl_l[128 + i];
    // permuted: storage idx = (col&15)*8 + (col>>4)
    btp[(i & 15)*8 + (i >> 4)] = bl_l[2*128 + i] + bl_l[3*128 + i];
  }
}

// ---------------- pack W[K][N] fp32 row-major into MFMA B-fragment order, bf16 ----------------
// slot layout: [kc = k/32][nt = n/16][lane = (kwithin/8)*16 + (n&15)][j = k&7]
__global__ void k_packW(const float* __restrict__ W, ushort* __restrict__ out, int K, int N){
  int o = blockIdx.x*256 + threadIdx.x;
  if (o >= K*N) return;
  int j   = o & 7;
  int lane = (o >> 3) & 63;
  int q   = lane >> 4, nl = lane & 15;
  int tl  = o >> 9;
  int nt  = tl % (N >> 4);
  int kc  = tl / (N >> 4);
  int k   = kc*32 + q*8 + j;
  int n   = nt*16 + nl;
  out[o] = f2bf(W[(size_t)k*N + n]);
}

// ---------------- segment sums into apcat = [a0 | a1 | xp] (NP x 384), xt in bf16 ----------------
__global__ __launch_bounds__(128) void k_segsum(
    const ushort* __restrict__ xt, const float* __restrict__ xp,
    const int* __restrict__ mrp, const int* __restrict__ mv,
    const int* __restrict__ crp, const int* __restrict__ cv,
    float* __restrict__ apcat){
  int p = blockIdx.x, c = threadIdx.x;
  float s0 = 0.f;
  {
    int j = mrp[p], je = mrp[p+1];
    for (; j + 4 <= je; j += 4){
      int i0 = mv[j], i1 = mv[j+1], i2 = mv[j+2], i3 = mv[j+3];
      float v0 = bf2f(xt[(size_t)i0*CDIM + c]);
      float v1 = bf2f(xt[(size_t)i1*CDIM + c]);
      float v2 = bf2f(xt[(size_t)i2*CDIM + c]);
      float v3 = bf2f(xt[(size_t)i3*CDIM + c]);
      s0 += (v0 + v1) + (v2 + v3);
    }
    for (; j < je; ++j) s0 += bf2f(xt[(size_t)mv[j]*CDIM + c]);
  }
  float s1 = 0.f;
  {
    int j = crp[p], je = crp[p+1];
    for (; j + 4 <= je; j += 4){
      int i0 = cv[j], i1 = cv[j+1], i2 = cv[j+2], i3 = cv[j+3];
      float v0 = bf2f(xt[(size_t)i0*CDIM + c]);
      float v1 = bf2f(xt[(size_t)i1*CDIM + c]);
      float v2 = bf2f(xt[(size_t)i2*CDIM + c]);
      float v3 = bf2f(xt[(size_t)i3*CDIM + c]);
      s1 += (v0 + v1) + (v2 + v3);
    }
    for (; j < je; ++j) s1 += bf2f(xt[(size_t)cv[j]*CDIM + c]);
  }
  apcat[(size_t)p*384 + c]       = s0;
  apcat[(size_t)p*384 + 128 + c] = s1;
  apcat[(size_t)p*384 + 256 + c] = xp[(size_t)p*CDIM + c];
}

// ---------------- edge aggregation: aggp[t] = perm-bf16( btp + yp2p[mentor] + sum yp3p[com] ) ----
// one half-wave (32 lanes) per thesis row; yp2p/yp3p/btp stored permuted fp32
__global__ __launch_bounds__(256) void k_agg(
    const int* __restrict__ mentor, const int* __restrict__ rowptr,
    const int* __restrict__ vals,
    const float* __restrict__ yp2p, const float* __restrict__ yp3p,
    const float* __restrict__ btp, ushort* __restrict__ aggp){
  int t = blockIdx.x*8 + (threadIdx.x >> 5);
  if (t >= NT) return;
  int i = threadIdx.x & 31;
  float4 s = *(const float4*)(btp + i*4);
  int m = mentor[t];
  float4 y = *(const float4*)(yp2p + (size_t)m*CDIM + i*4);
  s.x += y.x; s.y += y.y; s.z += y.z; s.w += y.w;
  int qb = rowptr[t], qe = rowptr[t+1];
  for (int q = qb; q < qe; ++q){
    float4 z = *(const float4*)(yp3p + (size_t)vals[q]*CDIM + i*4);
    s.x += z.x; s.y += z.y; s.z += z.z; s.w += z.w;
  }
  ushort4 o;
  o.x = f2bf(s.x); o.y = f2bf(s.y); o.z = f2bf(s.z); o.w = f2bf(s.w);
  *(ushort4*)(aggp + (size_t)t*CDIM + i*4) = o;
}

// ---------------- MFMA GEMM: Outbf[M,128] = bf16( A[M,K]@W + bias (+aggp) (+relu) ) --------------
// 256 thr = 4 waves in 2x2; wave computes 64x64 via 4x4 grid of 16x16x32 MFMA. BK=32.
template<int K, bool AF32, bool EPI, bool RELU>
__global__ __launch_bounds__(256) void k_mm(
    const void* __restrict__ Ain, int M,
    const ushort* __restrict__ Wfrag, const float* __restrict__ bias,
    ushort* __restrict__ Outbf, const ushort* __restrict__ aggp){
  __shared__ uint4 As[512];   // [rt 0..7][lane 0..63] 16B
  __shared__ uint4 Bs[512];   // [nt 0..7][lane 0..63] 16B
  const int tid  = threadIdx.x;
  const int lane = tid & 63;
  const int wave = tid >> 6;
  const int wr   = wave >> 1, wc = wave & 1;
  const int m0   = blockIdx.x * 128;
  const float* Af = (const float*)Ain;
  const ushort* Ab = (const ushort*)Ain;

  f32x4 acc[4][4];
  #pragma unroll
  for (int i = 0; i < 4; ++i)
    #pragma unroll
    for (int j = 0; j < 4; ++j) acc[i][j] = (f32x4)(0.f);

  const int rs = tid >> 2;   // staging row 0..63
  const int qs = tid & 3;    // staging k-octet 0..3

  for (int kc = 0; kc < K/32; ++kc){
    #pragma unroll
    for (int h = 0; h < 2; ++h){
      int rr = rs + 64*h;
      int grow = m0 + rr;
      uint4 payload = make_uint4(0,0,0,0);
      if (grow < M){
        if (AF32){
          const float* ap = Af + (size_t)grow*K + kc*32 + qs*8;
          float4 fa = *(const float4*)ap;
          float4 fb = *(const float4*)(ap + 4);
          payload.x = (uint)f2bf(fa.x) | ((uint)f2bf(fa.y) << 16);
          payload.y = (uint)f2bf(fa.z) | ((uint)f2bf(fa.w) << 16);
          payload.z = (uint)f2bf(fb.x) | ((uint)f2bf(fb.y) << 16);
          payload.w = (uint)f2bf(fb.z) | ((uint)f2bf(fb.w) << 16);
        } else {
          payload = *(const uint4*)(Ab + (size_t)grow*K + kc*32 + qs*8);
        }
      }
      As[(rr >> 4)*64 + qs*16 + (rr & 15)] = payload;
    }
    const uint4* wsrc = (const uint4*)Wfrag + (size_t)kc*512;
    Bs[tid]       = wsrc[tid];
    Bs[tid + 256] = wsrc[tid + 256];
    __syncthreads();

    bf16x8 a[4], b[4];
    #pragma unroll
    for (int i = 0; i < 4; ++i){ FragU u; u.u = As[(wr*4 + i)*64 + lane]; a[i] = u.b; }
    #pragma unroll
    for (int j = 0; j < 4; ++j){ FragU u; u.u = Bs[(wc*4 + j)*64 + lane]; b[j] = u.b; }
    #pragma unroll
    for (int i = 0; i < 4; ++i)
      #pragma unroll
      for (int j = 0; j < 4; ++j)
        acc[i][j] = __builtin_amdgcn_mfma_f32_16x16x32_bf16(a[i], b[j], acc[i][j], 0, 0, 0);
    __syncthreads();
  }

  // --- epilogue ---
  const int colb = wc*64 + (lane & 15);        // + j*16
  float bv[4];
  #pragma unroll
  for (int j = 0; j < 4; ++j) bv[j] = bias ? bias[colb + j*16] : 0.f;
  const int aoff = (lane & 15)*8 + wc*4;       // permuted: 4 consecutive bf16

  #pragma unroll
  for (int i = 0; i < 4; ++i){
    int r0 = m0 + wr*64 + i*16 + (lane >> 4)*4;
    #pragma unroll
    for (int reg = 0; reg < 4; ++reg){
      int row = r0 + reg;
      if (row >= M) continue;
      float s0 = bv[0], s1 = bv[1], s2 = bv[2], s3 = bv[3];
      if (EPI){
        ushort4 av = *(const ushort4*)(aggp + (size_t)row*CDIM + aoff);
        s0 += bf2f(av.x); s1 += bf2f(av.y); s2 += bf2f(av.z); s3 += bf2f(av.w);
      }
      float v0 = acc[i][0][reg] + s0;
      float v1 = acc[i][1][reg] + s1;
      float v2 = acc[i][2][reg] + s2;
      float v3 = acc[i][3][reg] + s3;
      if (RELU){
        v0 = v0 > 0.f ? v0 : 0.f; v1 = v1 > 0.f ? v1 : 0.f;
        v2 = v2 > 0.f ? v2 : 0.f; v3 = v3 > 0.f ? v3 : 0.f;
      }
      ushort* orow = Outbf + (size_t)row*CDIM + colb;
      orow[0]  = f2bf(v0); orow[16] = f2bf(v1);
      orow[32] = f2bf(v2); orow[48] = f2bf(v3);
    }
  }
}

// ---------------- MFMA GEMM N=32: zt[M,32] bf16 = Abf[M,128] @ Wfrag(128x32) ----------------
__global__ __launch_bounds__(256) void k_mm_n32(
    const ushort* __restrict__ Ab, int M,
    const ushort* __restrict__ Wfrag, ushort* __restrict__ Out){
  __shared__ uint4 As[512];
  __shared__ uint4 Bs[512];
  const int tid  = threadIdx.x;
  const int lane = tid & 63;
  const int w    = tid >> 6;
  const int m0   = blockIdx.x * 128;

  Bs[tid]       = ((const uint4*)Wfrag)[tid];
  Bs[tid + 256] = ((const uint4*)Wfrag)[tid + 256];

  f32x4 acc[2][2];
  #pragma unroll
  for (int i = 0; i < 2; ++i)
    #pragma unroll
    for (int j = 0; j < 2; ++j) acc[i][j] = (f32x4)(0.f);

  const int rs = tid >> 2, qs = tid & 3;
  for (int kc = 0; kc < 4; ++kc){
    #pragma unroll
    for (int h = 0; h < 2; ++h){
      int rr = rs + 64*h;
      int grow = m0 + rr;
      uint4 payload = make_uint4(0,0,0,0);
      if (grow < M)
        payload = *(const uint4*)(Ab + (size_t)grow*CDIM + kc*32 + qs*8);
      As[(rr >> 4)*64 + qs*16 + (rr & 15)] = payload;
    }
    __syncthreads();
    bf16x8 a[2], b[2];
    #pragma unroll
    for (int i = 0; i < 2; ++i){ FragU u; u.u = As[(w*2 + i)*64 + lane]; a[i] = u.b; }
    #pragma unroll
    for (int j = 0; j < 2; ++j){ FragU u; u.u = Bs[(kc*2 + j)*64 + lane]; b[j] = u.b; }
    #pragma unroll
    for (int i = 0; i < 2; ++i)
      #pragma unroll
      for (int j = 0; j < 2; ++j)
        acc[i][j] = __builtin_amdgcn_mfma_f32_16x16x32_bf16(a[i], b[j], acc[i][j], 0, 0, 0);
    __syncthreads();
  }

  #pragma unroll
  for (int i = 0; i < 2; ++i){
    int r0 = m0 + w*32 + i*16 + (lane >> 4)*4;
    #pragma unroll
    for (int reg = 0; reg < 4; ++reg){
      int row = r0 + reg;
      if (row >= M) continue;
      ushort* orow = Out + (size_t)row*32 + (lane & 15);
      orow[0]  = f2bf(acc[i][0][reg]);
      orow[16] = f2bf(acc[i][1][reg]);
    }
  }
}

// ---------------- fp32 GEMM (prof-side, small M); optional dual weight via blockIdx.y,
// optional permuted-output (for yp2p/yp3p) ----------------
template<int K, bool RELU, bool PERM>
__global__ __launch_bounds__(256) void k_gemm(
    const float* A, int M, const float* __restrict__ W0, const float* __restrict__ W1,
    const float* __restrict__ bias, float* Out0, float* Out1){
  const float* W = blockIdx.y ? W1 : W0;
  float* Out = blockIdx.y ? Out1 : Out0;
  __shared__ float As[64*36];
  __shared__ float Ws[32*128];
  const int tid  = threadIdx.x;
  const int m0   = blockIdx.x*64;
  const int c4   = (tid & 31)*4;
  const int rowg = tid >> 5;
  float4 acc[8];
  #pragma unroll
  for (int j = 0; j < 8; ++j) acc[j] = make_float4(0.f,0.f,0.f,0.f);

  for (int k0 = 0; k0 < K; k0 += 32){
    #pragma unroll
    for (int l = 0; l < 2; ++l){
      int q = tid + 256*l;
      int r = q >> 3, kf = q & 7;
      int row = m0 + r;
      float4 v = make_float4(0.f,0.f,0.f,0.f);
      if (row < M) v = *(const float4*)(A + (size_t)row*K + k0 + kf*4);
      *(float4*)&As[r*36 + kf*4] = v;
    }
    #pragma unroll
    for (int l = 0; l < 4; ++l){
      int q = tid + 256*l;
      int kk = q >> 5, cf = q & 31;
      *(float4*)&Ws[kk*128 + cf*4] = *(const float4*)(W + (size_t)(k0+kk)*128 + cf*4);
    }
    __syncthreads();
    #pragma unroll
    for (int k4 = 0; k4 < 8; ++k4){
      float4 w0 = *(const float4*)&Ws[(k4*4+0)*128 + c4];
      float4 w1 = *(const float4*)&Ws[(k4*4+1)*128 + c4];
      float4 w2 = *(const float4*)&Ws[(k4*4+2)*128 + c4];
      float4 w3 = *(const float4*)&Ws[(k4*4+3)*128 + c4];
      #pragma unroll
      for (int j = 0; j < 8; ++j){
        float4 a = *(const float4*)&As[(rowg + 8*j)*36 + k4*4];
        acc[j].x += a.x*w0.x + a.y*w1.x + a.z*w2.x + a.w*w3.x;
        acc[j].y += a.x*w0.y + a.y*w1.y + a.z*w2.y + a.w*w3.y;
        acc[j].z += a.x*w0.z + a.y*w1.z + a.z*w2.z + a.w*w3.z;
        acc[j].w += a.x*w0.w + a.y*w1.w + a.z*w2.w + a.w*w3.w;
      }
    }
    __syncthreads();
  }

  float4 bv = make_float4(0.f,0.f,0.f,0.f);
  if (bias) bv = *(const float4*)(bias + c4);
  #pragma unroll
  for (int j = 0; j < 8; ++j){
    int row = m0 + rowg + 8*j;
    if (row >= M) continue;
    float4 o = acc[j];
    o.x += bv.x; o.y += bv.y; o.z += bv.z; o.w += bv.w;
    if (RELU){
      o.x = o.x > 0.f ? o.x : 0.f; o.y = o.y > 0.f ? o.y : 0.f;
      o.z = o.z > 0.f ? o.z : 0.f; o.w = o.w > 0.f ? o.w : 0.f;
    }
    if (PERM){
      // storage idx = (col&15)*8 + (col>>4); c4%4==0 so the 4 cols share col>>4
      float* orow = Out + (size_t)row*CDIM + (c4 >> 4);
      orow[((c4 + 0) & 15)*8] = o.x;
      orow[((c4 + 1) & 15)*8] = o.y;
      orow[((c4 + 2) & 15)*8] = o.z;
      orow[((c4 + 3) & 15)*8] = o.w;
    } else {
      *(float4*)(Out + (size_t)row*CDIM + c4) = o;
    }
  }
}

// ---------------- N=32 fp32->bf16 GEMM (prof-side zpb/zpc), dual via blockIdx.y ----------------
__global__ __launch_bounds__(256) void k_gemm32(const float* __restrict__ A, int M,
                                                const float* __restrict__ W0,
                                                const float* __restrict__ W1,
                                                ushort* __restrict__ Out0,
                                                ushort* __restrict__ Out1){
  const float* W = blockIdx.y ? W1 : W0;
  ushort* Out = blockIdx.y ? Out1 : Out0;
  __shared__ float As[128*36];
  __shared__ float Ws[32*32];
  const int tid  = threadIdx.x;
  const int m0   = blockIdx.x*128;
  const int c4   = (tid & 7)*4;
  const int rowg = tid >> 3;
  float4 acc[4];
  #pragma unroll
  for (int j = 0; j < 4; ++j) acc[j] = make_float4(0.f,0.f,0.f,0.f);

  for (int k0 = 0; k0 < 128; k0 += 32){
    #pragma unroll
    for (int l = 0; l < 4; ++l){
      int q = tid + 256*l;
      int r = q >> 3, kf = q & 7;
      int row = m0 + r;
      float4 v = make_float4(0.f,0.f,0.f,0.f);
      if (row < M) v = *(const float4*)(A + (size_t)row*CDIM + k0 + kf*4);
      *(float4*)&As[r*36 + kf*4] = v;
    }
    {
      int kk = tid >> 3, cf = tid & 7;
      *(float4*)&Ws[kk*32 + cf*4] = *(const float4*)(W + (size_t)(k0+kk)*32 + cf*4);
    }
    __syncthreads();
    #pragma unroll
    for (int k4 = 0; k4 < 8; ++k4){
      float4 w0 = *(const float4*)&Ws[(k4*4+0)*32 + c4];
      float4 w1 = *(const float4*)&Ws[(k4*4+1)*32 + c4];
      float4 w2 = *(const float4*)&Ws[(k4*4+2)*32 + c4];
      float4 w3 = *(const float4*)&Ws[(k4*4+3)*32 + c4];
      #pragma unroll
      for (int j = 0; j < 4; ++j){
        float4 a = *(const float4*)&As[(rowg + 32*j)*36 + k4*4];
        acc[j].x += a.x*w0.x + a.y*w1.x + a.z*w2.x + a.w*w3.x;
        acc[j].y += a.x*w0.y + a.y*w1.y + a.z*w2.y + a.w*w3.y;
        acc[j].z += a.x*w0.z + a.y*w1.z + a.z*w2.z + a.w*w3.z;
        acc[j].w += a.x*w0.w + a.y*w1.w + a.z*w2.w + a.w*w3.w;
      }
    }
    __syncthreads();
  }
  #pragma unroll
  for (int j = 0; j < 4; ++j){
    int row = m0 + rowg + 32*j;
    if (row < M){
      ushort4 o;
      o.x = f2bf(acc[j].x); o.y = f2bf(acc[j].y);
      o.z = f2bf(acc[j].z); o.w = f2bf(acc[j].w);
      *(ushort4*)(Out + (size_t)row*32 + c4) = o;
    }
  }
}

// ---------------- edge classifier (bf16 z-vectors) ----------------
__global__ __launch_bounds__(256) void k_edge(
    const int* __restrict__ el0, const int* __restrict__ el1,
    const int* __restrict__ sup1,
    const ushort* __restrict__ zt, const ushort* __restrict__ zpb,
    const ushort* __restrict__ zpc,
    const float* __restrict__ b1, const float* __restrict__ W2,
    const float* __restrict__ b2, float* __restrict__ out, int n){
  __shared__ float sW[32], sb[32];
  if (threadIdx.x < 32){ sW[threadIdx.x] = W2[threadIdx.x]; sb[threadIdx.x] = b1[threadIdx.x]; }
  __syncthreads();
  int e = blockIdx.x*256 + threadIdx.x;
  if (e >= n) return;
  int t = el0[e], p = el1[e];
  int m = sup1[t];
  const uint4* zr = (const uint4*)(zt  + (size_t)t*32);
  const uint4* br = (const uint4*)(zpb + (size_t)m*32);
  const uint4* cr = (const uint4*)(zpc + (size_t)p*32);
  float acc = 0.f;
  #pragma unroll
  for (int i = 0; i < 4; ++i){
    uint4 ua = zr[i], ub = br[i], uc = cr[i];
    const uint aw[4] = {ua.x, ua.y, ua.z, ua.w};
    const uint bw[4] = {ub.x, ub.y, ub.z, ub.w};
    const uint cw[4] = {uc.x, uc.y, uc.z, uc.w};
    #pragma unroll
    for (int k = 0; k < 4; ++k){
      int base = i*8 + k*2;
      float h0 = bf2f((ushort)(aw[k] & 0xffff)) + bf2f((ushort)(bw[k] & 0xffff))
               + bf2f((ushort)(cw[k] & 0xffff)) + sb[base];
      float h1 = bf2f((ushort)(aw[k] >> 16)) + bf2f((ushort)(bw[k] >> 16))
               + bf2f((ushort)(cw[k] >> 16)) + sb[base + 1];
      h0 = h0 > 0.f ? h0 : 0.f;
      h1 = h1 > 0.f ? h1 : 0.f;
      acc = fmaf(h0, sW[base], acc);
      acc = fmaf(h1, sW[base + 1], acc);
    }
  }
  out[e] = acc + b2[0];
}

// ---------------- launch ----------------
extern "C" void kernel_launch(void* const* d_in, const int* in_sizes, int n_in,
                              void* d_out, int out_size, void* d_ws, size_t ws_size,
                              hipStream_t stream){
  const float* thesis_x = (const float*)d_in[0];
  const float* lin_W    = (const float*)d_in[1];
  const float* lin_b    = (const float*)d_in[2];
  const float* prof_emb = (const float*)d_in[3];
  const float* gWl      = (const float*)d_in[4];
  const float* gbl      = (const float*)d_in[5];
  const float* gWr      = (const float*)d_in[6];
  const float* cW1      = (const float*)d_in[7];
  const float* cb1      = (const float*)d_in[8];
  const float* cW2      = (const float*)d_in[9];
  const float* cb2      = (const float*)d_in[10];
  const int*   pid      = (const int*)d_in[11];
  const int*   sup0     = (const int*)d_in[12];
  const int*   sup1     = sup0 + NT;
  const int*   com0     = (const int*)d_in[13];
  const int*   com1     = com0 + EC;
  const int*   el0      = (const int*)d_in[14];
  const int*   el1      = el0 + EL;
  float* outp = (float*)d_out;

  char* base = (char*)d_ws;
  size_t off = 0;
  auto alloc = [&](size_t bytes)->void*{
    void* p = base + off;
    off += (bytes + 255) & ~(size_t)255;
    return p;
  };
  ushort* xt     = (ushort*)alloc((size_t)NT*CDIM*2);     // bf16 activations
  ushort* aggp   = (ushort*)alloc((size_t)NT*CDIM*2);     // bf16 permuted agg; zt aliases later
  float*  xp     = (float*)alloc((size_t)NP*CDIM*4);
  float*  apcat  = (float*)alloc((size_t)NP*384*4);
  float*  yp2p   = (float*)alloc((size_t)NP*CDIM*4);      // permuted fp32
  float*  yp3p   = (float*)alloc((size_t)NP*CDIM*4);      // permuted fp32
  float*  Wp     = (float*)alloc((size_t)384*128*4);
  float*  Wt     = (float*)alloc((size_t)128*128*4);
  float*  bp     = (float*)alloc(512);
  float*  btp    = (float*)alloc(512);
  ushort* WmFrag = (ushort*)alloc((size_t)384*128*2);
  ushort* WtFrag = (ushort*)alloc((size_t)128*128*2);
  ushort* W1aFrag= (ushort*)alloc((size_t)128*32*2);
  ushort* zpb    = (ushort*)alloc((size_t)NP*32*2);
  ushort* zpc    = (ushort*)alloc((size_t)NP*32*2);
  int* rp_t    = (int*)alloc((size_t)(NT+1)*4);
  int* v_t     = (int*)alloc((size_t)EC*4);
  int* rp_c1   = (int*)alloc((size_t)(NP+1)*4);
  int* v_c1    = (int*)alloc((size_t)EC*4);
  int* rp_m    = (int*)alloc((size_t)(NP+1)*4);
  int* v_m     = (int*)alloc((size_t)NT*4);
  int* counts  = (int*)alloc((size_t)NT*4);
  int* cursor  = (int*)alloc((size_t)NT*4);
  int* partials= (int*)alloc(4096);
  ushort* zt   = aggp;   // alias: aggp dead after last k_mm EPI, zt written after

  auto cdiv = [](int a, int b){ return (a + b - 1)/b; };

  auto build_csr = [&](const int* keys, const int* storev, int ne, int nb,
                       int* rowptr, int* vals){
    hipMemsetAsync(counts, 0, (size_t)nb*4, stream);
    k_hist<<<cdiv(ne,256),256,0,stream>>>(keys, ne, counts);
    int nPb = cdiv(nb,256);
    k_partial<<<nPb,256,0,stream>>>(counts, nb, partials);
    k_scan_partials<<<1,1024,0,stream>>>(partials, nPb, rowptr + nb);
    k_scan_final<<<nPb,256,0,stream>>>(counts, partials, nb, rowptr);
    k_copy_int<<<cdiv(nb,256),256,0,stream>>>(rowptr, cursor, nb);
    k_fill<<<cdiv(ne,256),256,0,stream>>>(keys, storev, ne, cursor, vals);
  };

  build_csr(com0, com1, EC, NT, rp_t,  v_t);
  build_csr(com1, com0, EC, NP, rp_c1, v_c1);
  build_csr(sup1, sup0, NT, NP, rp_m,  v_m);

  k_xp_init<<<cdiv(NP*CDIM,256),256,0,stream>>>(prof_emb, pid, xp);

  k_packW<<<cdiv(384*128,256),256,0,stream>>>(lin_W, WmFrag, 384, 128);
  k_mm<384,true,false,false><<<cdiv(NT,128),256,0,stream>>>(
      thesis_x, NT, WmFrag, lin_b, xt, nullptr);

  for (int l = 0; l < 2; ++l){
    k_wcombine<<<64,256,0,stream>>>(gWl, gbl, gWr, l, Wp, bp, Wt, btp);
    k_packW<<<cdiv(128*128,256),256,0,stream>>>(Wt, WtFrag, 128, 128);
    k_segsum<<<NP,128,0,stream>>>(xt, xp, rp_m, v_m, rp_c1, v_c1, apcat);
    // yp2p = perm(xp @ Wl2), yp3p = perm(xp @ Wl3)  (old xp), dual launch
    k_gemm<128,false,true><<<dim3(cdiv(NP,64),2),256,0,stream>>>(
        xp, NP, gWl + (size_t)(l*4+2)*16384, gWl + (size_t)(l*4+3)*16384,
        nullptr, yp2p, yp3p);
    // aggp = bf16-perm(btp + yp2p[mentor] + sum yp3p[committee])
    k_agg<<<cdiv(NT,8),256,0,stream>>>(sup1, rp_t, v_t, yp2p, yp3p, btp, aggp);
    if (l == 0){
      k_gemm<384,true,false><<<cdiv(NP,64),256,0,stream>>>(
          apcat, NP, Wp, nullptr, bp, xp, nullptr);
      k_mm<128,false,true,true><<<cdiv(NT,128),256,0,stream>>>(
          xt, NT, WtFrag, nullptr, xt, aggp);
    } else {
      k_gemm<384,false,false><<<cdiv(NP,64),256,0,stream>>>(
          apcat, NP, Wp, nullptr, bp, xp, nullptr);
      k_mm<128,false,true,false><<<cdiv(NT,128),256,0,stream>>>(
          xt, NT, WtFrag, nullptr, xt, aggp);
    }
  }

  // classifier precomputes (zt aliases aggp — safe, aggp consumed above)
  k_packW<<<cdiv(128*32,256),256,0,stream>>>(cW1, W1aFrag, 128, 32);
  k_mm_n32<<<cdiv(NT,128),256,0,stream>>>(xt, NT, W1aFrag, zt);
  k_gemm32<<<dim3(cdiv(NP,128),2),256,0,stream>>>(
      xp, NP, cW1 + 128*32, cW1 + 256*32, zpb, zpc);
  k_edge<<<cdiv(EL,256),256,0,stream>>>(el0, el1, sup1, zt, zpb, zpc,
                                        cb1, cW2, cb2, outp, EL);
}

// Round 4
// 1022.284 us; speedup vs baseline: 2.2909x; 1.1051x over previous
//
#include <hip/hip_runtime.h>
#include <hip/hip_bf16.h>
#include <cstdint>
#include <cstddef>

#define NT 200000
#define NP 5000
#define FDIM 384
#define CDIM 128
#define EC 600000
#define EL 400000
#define NKEYS (NT + 2*NP)          // concatenated CSR segment count
#define NEDGE (2*EC + NT)          // concatenated edge count

typedef unsigned int uint;
typedef unsigned short ushort;
typedef __attribute__((ext_vector_type(8))) __bf16 bf16x8;
typedef __attribute__((ext_vector_type(4))) float f32x4;

union FragU { uint4 u; bf16x8 b; };

__device__ __forceinline__ ushort f2bf(float f){
  uint u = __float_as_uint(f);
  u = (u + 0x7fffu + ((u >> 16) & 1u)) >> 16;
  return (ushort)u;
}
__device__ __forceinline__ float bf2f(ushort h){
  return __uint_as_float(((uint)h) << 16);
}

// ---------------- fused CSR build (3 CSRs in one counting sort) ----------------
// counts layout: [thesis(com) NT | prof(com) NP | prof(sup) NP]; vals global.
__global__ void k_hist3(const int* __restrict__ com0, const int* __restrict__ com1,
                        const int* __restrict__ sup1, int* __restrict__ counts){
  int i = blockIdx.x*256 + threadIdx.x;
  if (i < EC)            atomicAdd(&counts[com0[i]], 1);
  else if (i < 2*EC)     atomicAdd(&counts[NT + com1[i - EC]], 1);
  else if (i < NEDGE)    atomicAdd(&counts[NT + NP + sup1[i - 2*EC]], 1);
}

__global__ void k_partial(const int* __restrict__ counts, int n, int* __restrict__ partials){
  __shared__ int s[256];
  int i = blockIdx.x*256 + threadIdx.x;
  s[threadIdx.x] = (i < n) ? counts[i] : 0;
  __syncthreads();
  for (int off = 128; off > 0; off >>= 1){
    if (threadIdx.x < off) s[threadIdx.x] += s[threadIdx.x + off];
    __syncthreads();
  }
  if (threadIdx.x == 0) partials[blockIdx.x] = s[0];
}

__global__ void k_scan_partials(int* __restrict__ partials, int nP, int* __restrict__ total_out){
  __shared__ int s[1024];
  int carry = 0;
  for (int base = 0; base < nP; base += 1024){
    int i = base + threadIdx.x;
    int v = (i < nP) ? partials[i] : 0;
    s[threadIdx.x] = v; __syncthreads();
    for (int off = 1; off < 1024; off <<= 1){
      int t = (threadIdx.x >= off) ? s[threadIdx.x - off] : 0;
      __syncthreads();
      s[threadIdx.x] += t;
      __syncthreads();
    }
    if (i < nP) partials[i] = carry + s[threadIdx.x] - v;  // exclusive
    int chunk_total = s[1023];
    __syncthreads();
    carry += chunk_total;
  }
  if (threadIdx.x == 0 && total_out) *total_out = carry;
}

__global__ void k_scan_final(const int* __restrict__ counts, const int* __restrict__ pscan,
                             int n, int* __restrict__ rowptr){
  __shared__ int s[256];
  int tid = threadIdx.x;
  int i = blockIdx.x*256 + tid;
  int v = (i < n) ? counts[i] : 0;
  s[tid] = v; __syncthreads();
  for (int off = 1; off < 256; off <<= 1){
    int t = (tid >= off) ? s[tid - off] : 0;
    __syncthreads();
    s[tid] += t;
    __syncthreads();
  }
  if (i < n) rowptr[i] = pscan[blockIdx.x] + s[tid] - v;
}

__global__ void k_copy_int(const int* __restrict__ src, int* __restrict__ dst, int n){
  int i = blockIdx.x*256 + threadIdx.x;
  if (i < n) dst[i] = src[i];
}

__global__ void k_fill3(const int* __restrict__ com0, const int* __restrict__ com1,
                        const int* __restrict__ sup0, const int* __restrict__ sup1,
                        int* __restrict__ cursor, int* __restrict__ vals){
  int i = blockIdx.x*256 + threadIdx.x;
  int key, sv;
  if (i < EC)          { key = com0[i];                 sv = com1[i]; }
  else if (i < 2*EC)   { key = NT + com1[i - EC];       sv = com0[i - EC]; }
  else if (i < NEDGE)  { key = NT + NP + sup1[i - 2*EC]; sv = sup0[i - 2*EC]; }
  else return;
  int pos = atomicAdd(&cursor[key], 1);
  vals[pos] = sv;
}

// ---------------- prep: xp init + natural pack(lin_W) + perm pack(cW1a) ----------------
// natural pack slot: [kc=k/32][nt][lane=(k/8%4)*16+(n&15)][j=k&7]
// perm    pack slot: same slots but k = 4*kc + q + 16*j  (matches permuted-A groups)
__global__ void k_prep(const float* __restrict__ pe, const int* __restrict__ pid,
                       float* __restrict__ xp,
                       const float* __restrict__ lin_W, ushort* __restrict__ WmFrag,
                       const float* __restrict__ cW1, ushort* __restrict__ W1aFrag){
  int i = blockIdx.x*256 + threadIdx.x;
  if (i < NP*CDIM){
    xp[i] = pe[(size_t)pid[i >> 7]*CDIM + (i & 127)];
    return;
  }
  i -= NP*CDIM;
  if (i < 384*128){   // natural pack, N=128
    int j = i & 7, lane = (i >> 3) & 63, q = lane >> 4, nl = lane & 15, tl = i >> 9;
    int nt = tl & 7, kc = tl >> 3;
    int k = kc*32 + q*8 + j, n = nt*16 + nl;
    WmFrag[i] = f2bf(lin_W[(size_t)k*128 + n]);
    return;
  }
  i -= 384*128;
  if (i < 128*32){    // perm pack, N=32
    int j = i & 7, lane = (i >> 3) & 63, q = lane >> 4, nl = lane & 15, tl = i >> 9;
    int nt = tl & 1, kc = tl >> 1;
    int k = 4*kc + q + 16*j, n = nt*16 + nl;
    W1aFrag[i] = f2bf(cW1[(size_t)k*32 + n]);
  }
}

// ---------------- weight combine per layer (+ direct frag pack of Wt) ----------------
// Wp rows 0..255 carry the k-permutation of the permuted xt storage; block 2 (xp) natural.
__global__ void k_wcombine(const float* __restrict__ gWl, const float* __restrict__ gbl,
                           const float* __restrict__ gWr, int layer,
                           float* __restrict__ Wp, float* __restrict__ bp,
                           ushort* __restrict__ WtFrag, float* __restrict__ btp){
  int i = blockIdx.x*256 + threadIdx.x;
  const float* Wl_l = gWl + (size_t)layer*4*16384;
  const float* Wr_l = gWr + (size_t)layer*4*16384;
  const float* bl_l = gbl + (size_t)layer*4*128;
  if (i < 16384){
    int r = i >> 7, n = i & 127;
    int c = ((r >> 2) & 1)*64 + (r & 3)*16 + (r >> 3);   // logical col at storage pos r
    Wp[i]         = Wl_l[(size_t)c*128 + n];
    Wp[16384 + i] = Wl_l[16384 + (size_t)c*128 + n];
    Wp[32768 + i] = Wr_l[i] + Wr_l[16384 + i];           // xp block, natural
    // WtFrag: perm pack of Wr2+Wr3 at (k=r, n)
    float wt = Wr_l[2*16384 + i] + Wr_l[3*16384 + i];
    int j = r >> 4, rem = r & 15, kc = rem >> 2, q = rem & 3, nt = n >> 4, nl = n & 15;
    WtFrag[((size_t)(kc*8 + nt)*64 + q*16 + nl)*8 + j] = f2bf(wt);
  }
  if (i < 128){
    bp[i] = bl_l[i] + bl_l[128 + i];
    btp[(i & 15)*8 + (i >> 4)] = bl_l[2*128 + i] + bl_l[3*128 + i];
  }
}

// ---------------- segment sums: wave per prof, dword loads of permuted-bf16 xt ----------------
// apcat = [a0 | a1 | xp] (NP x 384); a0/a1 stay in xt's permuted storage order.
__global__ __launch_bounds__(256) void k_segsum(
    const uint* __restrict__ xt32, const float* __restrict__ xp,
    const int* __restrict__ mrp, const int* __restrict__ crp,
    const int* __restrict__ vall, float* __restrict__ apcat){
  int p = blockIdx.x*4 + (threadIdx.x >> 6);
  if (p >= NP) return;
  int lane = threadIdx.x & 63;
  float s0a = 0.f, s0b = 0.f;
  {
    int j = mrp[p], je = mrp[p+1];
    for (; j + 4 <= je; j += 4){
      uint v0 = xt32[(size_t)vall[j]  *64 + lane];
      uint v1 = xt32[(size_t)vall[j+1]*64 + lane];
      uint v2 = xt32[(size_t)vall[j+2]*64 + lane];
      uint v3 = xt32[(size_t)vall[j+3]*64 + lane];
      s0a += (bf2f((ushort)(v0 & 0xffff)) + bf2f((ushort)(v1 & 0xffff)))
           + (bf2f((ushort)(v2 & 0xffff)) + bf2f((ushort)(v3 & 0xffff)));
      s0b += (bf2f((ushort)(v0 >> 16)) + bf2f((ushort)(v1 >> 16)))
           + (bf2f((ushort)(v2 >> 16)) + bf2f((ushort)(v3 >> 16)));
    }
    for (; j < je; ++j){
      uint v = xt32[(size_t)vall[j]*64 + lane];
      s0a += bf2f((ushort)(v & 0xffff));
      s0b += bf2f((ushort)(v >> 16));
    }
  }
  float s1a = 0.f, s1b = 0.f;
  {
    int j = crp[p], je = crp[p+1];
    for (; j + 4 <= je; j += 4){
      uint v0 = xt32[(size_t)vall[j]  *64 + lane];
      uint v1 = xt32[(size_t)vall[j+1]*64 + lane];
      uint v2 = xt32[(size_t)vall[j+2]*64 + lane];
      uint v3 = xt32[(size_t)vall[j+3]*64 + lane];
      s1a += (bf2f((ushort)(v0 & 0xffff)) + bf2f((ushort)(v1 & 0xffff)))
           + (bf2f((ushort)(v2 & 0xffff)) + bf2f((ushort)(v3 & 0xffff)));
      s1b += (bf2f((ushort)(v0 >> 16)) + bf2f((ushort)(v1 >> 16)))
           + (bf2f((ushort)(v2 >> 16)) + bf2f((ushort)(v3 >> 16)));
    }
    for (; j < je; ++j){
      uint v = xt32[(size_t)vall[j]*64 + lane];
      s1a += bf2f((ushort)(v & 0xffff));
      s1b += bf2f((ushort)(v >> 16));
    }
  }
  float* row = apcat + (size_t)p*384;
  row[2*lane]       = s0a; row[2*lane + 1]       = s0b;
  row[128 + 2*lane] = s1a; row[128 + 2*lane + 1] = s1b;
  float2 xv = *(const float2*)(xp + (size_t)p*CDIM + 2*lane);
  row[256 + 2*lane] = xv.x; row[256 + 2*lane + 1] = xv.y;
}

// ---------------- edge aggregation: aggp[t] = perm-bf16( btp + yp2p[mentor] + sum yp3p ) ----
__global__ __launch_bounds__(256) void k_agg(
    const int* __restrict__ mentor, const int* __restrict__ rowptr,
    const int* __restrict__ vals,
    const float* __restrict__ yp2p, const float* __restrict__ yp3p,
    const float* __restrict__ btp, ushort* __restrict__ aggp){
  int t = blockIdx.x*8 + (threadIdx.x >> 5);
  if (t >= NT) return;
  int i = threadIdx.x & 31;
  float4 s = *(const float4*)(btp + i*4);
  int m = mentor[t];
  float4 y = *(const float4*)(yp2p + (size_t)m*CDIM + i*4);
  s.x += y.x; s.y += y.y; s.z += y.z; s.w += y.w;
  int qb = rowptr[t], qe = rowptr[t+1];
  for (int q = qb; q < qe; ++q){
    float4 z = *(const float4*)(yp3p + (size_t)vals[q]*CDIM + i*4);
    s.x += z.x; s.y += z.y; s.z += z.z; s.w += z.w;
  }
  ushort4 o;
  o.x = f2bf(s.x); o.y = f2bf(s.y); o.z = f2bf(s.z); o.w = f2bf(s.w);
  *(ushort4*)(aggp + (size_t)t*CDIM + i*4) = o;
}

// ---------------- MFMA GEMM: permuted-bf16 out; A = fp32 natural (AF32) or bf16 permuted -------
// 256 thr = 4 waves 2x2; wave does 64x64 via 4x4 16x16x32 MFMA. BK=32.
template<int K, bool AF32, bool EPI, bool RELU>
__global__ __launch_bounds__(256) void k_mm(
    const void* __restrict__ Ain, int M,
    const ushort* __restrict__ Wfrag, const float* __restrict__ bias,
    ushort* __restrict__ Outp, const ushort* __restrict__ aggp){
  __shared__ uint4 As[512];
  __shared__ uint4 Bs[512];
  const int tid  = threadIdx.x;
  const int lane = tid & 63;
  const int wave = tid >> 6;
  const int wr   = wave >> 1, wc = wave & 1;
  const int m0   = blockIdx.x * 128;
  const float* Af = (const float*)Ain;
  const ushort* Ab = (const ushort*)Ain;

  f32x4 acc[4][4];
  #pragma unroll
  for (int i = 0; i < 4; ++i)
    #pragma unroll
    for (int j = 0; j < 4; ++j) acc[i][j] = (f32x4)(0.f);

  for (int kc = 0; kc < K/32; ++kc){
    if (AF32){
      const int rs = tid >> 2, qs = tid & 3;
      #pragma unroll
      for (int h = 0; h < 2; ++h){
        int rr = rs + 64*h;
        int grow = m0 + rr;
        uint4 payload = make_uint4(0,0,0,0);
        if (grow < M){
          const float* ap = Af + (size_t)grow*K + kc*32 + qs*8;
          float4 fa = *(const float4*)ap;
          float4 fb = *(const float4*)(ap + 4);
          payload.x = (uint)f2bf(fa.x) | ((uint)f2bf(fa.y) << 16);
          payload.y = (uint)f2bf(fa.z) | ((uint)f2bf(fa.w) << 16);
          payload.z = (uint)f2bf(fb.x) | ((uint)f2bf(fb.y) << 16);
          payload.w = (uint)f2bf(fb.z) | ((uint)f2bf(fb.w) << 16);
        }
        As[(rr >> 4)*64 + qs*16 + (rr & 15)] = payload;
      }
    } else {
      // permuted A: group t = 4kc+q is 16 contiguous bytes in storage
      #pragma unroll
      for (int h = 0; h < 2; ++h){
        int e = tid + 256*h;
        int rr = e >> 2, q = e & 3;
        int grow = m0 + rr;
        uint4 payload = make_uint4(0,0,0,0);
        if (grow < M)
          payload = *(const uint4*)(Ab + (size_t)grow*K + (4*kc + q)*8);
        As[(rr >> 4)*64 + q*16 + (rr & 15)] = payload;
      }
    }
    const uint4* wsrc = (const uint4*)Wfrag + (size_t)kc*512;
    Bs[tid]       = wsrc[tid];
    Bs[tid + 256] = wsrc[tid + 256];
    __syncthreads();

    bf16x8 a[4], b[4];
    #pragma unroll
    for (int i = 0; i < 4; ++i){ FragU u; u.u = As[(wr*4 + i)*64 + lane]; a[i] = u.b; }
    #pragma unroll
    for (int j = 0; j < 4; ++j){ FragU u; u.u = Bs[(wc*4 + j)*64 + lane]; b[j] = u.b; }
    #pragma unroll
    for (int i = 0; i < 4; ++i)
      #pragma unroll
      for (int j = 0; j < 4; ++j)
        acc[i][j] = __builtin_amdgcn_mfma_f32_16x16x32_bf16(a[i], b[j], acc[i][j], 0, 0, 0);
    __syncthreads();
  }

  // --- epilogue: store permuted ushort4 per row ---
  const int nl = lane & 15;
  float bv[4];
  #pragma unroll
  for (int j = 0; j < 4; ++j) bv[j] = bias ? bias[wc*64 + j*16 + nl] : 0.f;
  const int s0 = nl*8 + wc*4;

  #pragma unroll
  for (int i = 0; i < 4; ++i){
    int r0 = m0 + wr*64 + i*16 + (lane >> 4)*4;
    #pragma unroll
    for (int reg = 0; reg < 4; ++reg){
      int row = r0 + reg;
      if (row >= M) continue;
      float v0 = acc[i][0][reg] + bv[0];
      float v1 = acc[i][1][reg] + bv[1];
      float v2 = acc[i][2][reg] + bv[2];
      float v3 = acc[i][3][reg] + bv[3];
      if (EPI){
        ushort4 av = *(const ushort4*)(aggp + (size_t)row*CDIM + s0);
        v0 += bf2f(av.x); v1 += bf2f(av.y); v2 += bf2f(av.z); v3 += bf2f(av.w);
      }
      if (RELU){
        v0 = v0 > 0.f ? v0 : 0.f; v1 = v1 > 0.f ? v1 : 0.f;
        v2 = v2 > 0.f ? v2 : 0.f; v3 = v3 > 0.f ? v3 : 0.f;
      }
      ushort4 o;
      o.x = f2bf(v0); o.y = f2bf(v1); o.z = f2bf(v2); o.w = f2bf(v3);
      *(ushort4*)(Outp + (size_t)row*CDIM + s0) = o;
    }
  }
}

// ---------------- MFMA GEMM N=32: zt[M,32] bf16-natural = xt_perm[M,128] @ W1aFrag ----------------
__global__ __launch_bounds__(256) void k_mm_n32(
    const ushort* __restrict__ Ab, int M,
    const ushort* __restrict__ Wfrag, ushort* __restrict__ Out){
  __shared__ uint4 As[512];
  __shared__ uint4 Bs[512];
  const int tid  = threadIdx.x;
  const int lane = tid & 63;
  const int w    = tid >> 6;
  const int m0   = blockIdx.x * 128;

  Bs[tid]       = ((const uint4*)Wfrag)[tid];
  Bs[tid + 256] = ((const uint4*)Wfrag)[tid + 256];

  f32x4 acc[2][2];
  #pragma unroll
  for (int i = 0; i < 2; ++i)
    #pragma unroll
    for (int j = 0; j < 2; ++j) acc[i][j] = (f32x4)(0.f);

  for (int kc = 0; kc < 4; ++kc){
    #pragma unroll
    for (int h = 0; h < 2; ++h){
      int e = tid + 256*h;
      int rr = e >> 2, q = e & 3;
      int grow = m0 + rr;
      uint4 payload = make_uint4(0,0,0,0);
      if (grow < M)
        payload = *(const uint4*)(Ab + (size_t)grow*CDIM + (4*kc + q)*8);
      As[(rr >> 4)*64 + q*16 + (rr & 15)] = payload;
    }
    __syncthreads();
    bf16x8 a[2], b[2];
    #pragma unroll
    for (int i = 0; i < 2; ++i){ FragU u; u.u = As[(w*2 + i)*64 + lane]; a[i] = u.b; }
    #pragma unroll
    for (int j = 0; j < 2; ++j){ FragU u; u.u = Bs[(kc*2 + j)*64 + lane]; b[j] = u.b; }
    #pragma unroll
    for (int i = 0; i < 2; ++i)
      #pragma unroll
      for (int j = 0; j < 2; ++j)
        acc[i][j] = __builtin_amdgcn_mfma_f32_16x16x32_bf16(a[i], b[j], acc[i][j], 0, 0, 0);
    __syncthreads();
  }

  #pragma unroll
  for (int i = 0; i < 2; ++i){
    int r0 = m0 + w*32 + i*16 + (lane >> 4)*4;
    #pragma unroll
    for (int reg = 0; reg < 4; ++reg){
      int row = r0 + reg;
      if (row >= M) continue;
      ushort* orow = Out + (size_t)row*32 + (lane & 15);
      orow[0]  = f2bf(acc[i][0][reg]);
      orow[16] = f2bf(acc[i][1][reg]);
    }
  }
}

// ---------------- fused prof-side fp32 GEMM: blockIdx.y = {xp-update, yp2, yp3} ----------------
__global__ __launch_bounds__(256) void k_gemm3(
    const float* __restrict__ apcat, const float* __restrict__ xpold, int layer,
    const float* __restrict__ Wp, const float* __restrict__ gWl,
    const float* __restrict__ bp, float* __restrict__ xpnew,
    float* __restrict__ yp2p, float* __restrict__ yp3p){
  const int y = blockIdx.y;
  const float* A; const float* W; const float* bias; float* Out;
  int K; bool relu, perm;
  if (y == 0){ A = apcat; K = 384; W = Wp; bias = bp; Out = xpnew;
               relu = (layer == 0); perm = false; }
  else       { A = xpold; K = 128; W = gWl + (size_t)(layer*4 + 1 + y)*16384;
               bias = nullptr; Out = (y == 1) ? yp2p : yp3p; relu = false; perm = true; }

  __shared__ float As[64*36];
  __shared__ float Ws[32*128];
  const int tid  = threadIdx.x;
  const int m0   = blockIdx.x*64;
  const int c4   = (tid & 31)*4;
  const int rowg = tid >> 5;
  float4 acc[8];
  #pragma unroll
  for (int j = 0; j < 8; ++j) acc[j] = make_float4(0.f,0.f,0.f,0.f);

  for (int k0 = 0; k0 < K; k0 += 32){
    #pragma unroll
    for (int l = 0; l < 2; ++l){
      int q = tid + 256*l;
      int r = q >> 3, kf = q & 7;
      int row = m0 + r;
      float4 v = make_float4(0.f,0.f,0.f,0.f);
      if (row < NP) v = *(const float4*)(A + (size_t)row*K + k0 + kf*4);
      *(float4*)&As[r*36 + kf*4] = v;
    }
    #pragma unroll
    for (int l = 0; l < 4; ++l){
      int q = tid + 256*l;
      int kk = q >> 5, cf = q & 31;
      *(float4*)&Ws[kk*128 + cf*4] = *(const float4*)(W + (size_t)(k0+kk)*128 + cf*4);
    }
    __syncthreads();
    #pragma unroll
    for (int k4 = 0; k4 < 8; ++k4){
      float4 w0 = *(const float4*)&Ws[(k4*4+0)*128 + c4];
      float4 w1 = *(const float4*)&Ws[(k4*4+1)*128 + c4];
      float4 w2 = *(const float4*)&Ws[(k4*4+2)*128 + c4];
      float4 w3 = *(const float4*)&Ws[(k4*4+3)*128 + c4];
      #pragma unroll
      for (int j = 0; j < 8; ++j){
        float4 a = *(const float4*)&As[(rowg + 8*j)*36 + k4*4];
        acc[j].x += a.x*w0.x + a.y*w1.x + a.z*w2.x + a.w*w3.x;
        acc[j].y += a.x*w0.y + a.y*w1.y + a.z*w2.y + a.w*w3.y;
        acc[j].z += a.x*w0.z + a.y*w1.z + a.z*w2.z + a.w*w3.z;
        acc[j].w += a.x*w0.w + a.y*w1.w + a.z*w2.w + a.w*w3.w;
      }
    }
    __syncthreads();
  }

  float4 bv = make_float4(0.f,0.f,0.f,0.f);
  if (bias) bv = *(const float4*)(bias + c4);
  #pragma unroll
  for (int j = 0; j < 8; ++j){
    int row = m0 + rowg + 8*j;
    if (row >= NP) continue;
    float4 o = acc[j];
    o.x += bv.x; o.y += bv.y; o.z += bv.z; o.w += bv.w;
    if (relu){
      o.x = o.x > 0.f ? o.x : 0.f; o.y = o.y > 0.f ? o.y : 0.f;
      o.z = o.z > 0.f ? o.z : 0.f; o.w = o.w > 0.f ? o.w : 0.f;
    }
    if (perm){
      float* orow = Out + (size_t)row*CDIM + (c4 >> 4);
      orow[((c4 + 0) & 15)*8] = o.x;
      orow[((c4 + 1) & 15)*8] = o.y;
      orow[((c4 + 2) & 15)*8] = o.z;
      orow[((c4 + 3) & 15)*8] = o.w;
    } else {
      *(float4*)(Out + (size_t)row*CDIM + c4) = o;
    }
  }
}

// ---------------- N=32 fp32->bf16 GEMM (prof-side zpb/zpc), dual via blockIdx.y ----------------
__global__ __launch_bounds__(256) void k_gemm32(const float* __restrict__ A, int M,
                                                const float* __restrict__ W0,
                                                const float* __restrict__ W1,
                                                ushort* __restrict__ Out0,
                                                ushort* __restrict__ Out1){
  const float* W = blockIdx.y ? W1 : W0;
  ushort* Out = blockIdx.y ? Out1 : Out0;
  __shared__ float As[128*36];
  __shared__ float Ws[32*32];
  const int tid  = threadIdx.x;
  const int m0   = blockIdx.x*128;
  const int c4   = (tid & 7)*4;
  const int rowg = tid >> 3;
  float4 acc[4];
  #pragma unroll
  for (int j = 0; j < 4; ++j) acc[j] = make_float4(0.f,0.f,0.f,0.f);

  for (int k0 = 0; k0 < 128; k0 += 32){
    #pragma unroll
    for (int l = 0; l < 4; ++l){
      int q = tid + 256*l;
      int r = q >> 3, kf = q & 7;
      int row = m0 + r;
      float4 v = make_float4(0.f,0.f,0.f,0.f);
      if (row < M) v = *(const float4*)(A + (size_t)row*CDIM + k0 + kf*4);
      *(float4*)&As[r*36 + kf*4] = v;
    }
    {
      int kk = tid >> 3, cf = tid & 7;
      *(float4*)&Ws[kk*32 + cf*4] = *(const float4*)(W + (size_t)(k0+kk)*32 + cf*4);
    }
    __syncthreads();
    #pragma unroll
    for (int k4 = 0; k4 < 8; ++k4){
      float4 w0 = *(const float4*)&Ws[(k4*4+0)*32 + c4];
      float4 w1 = *(const float4*)&Ws[(k4*4+1)*32 + c4];
      float4 w2 = *(const float4*)&Ws[(k4*4+2)*32 + c4];
      float4 w3 = *(const float4*)&Ws[(k4*4+3)*32 + c4];
      #pragma unroll
      for (int j = 0; j < 4; ++j){
        float4 a = *(const float4*)&As[(rowg + 32*j)*36 + k4*4];
        acc[j].x += a.x*w0.x + a.y*w1.x + a.z*w2.x + a.w*w3.x;
        acc[j].y += a.x*w0.y + a.y*w1.y + a.z*w2.y + a.w*w3.y;
        acc[j].z += a.x*w0.z + a.y*w1.z + a.z*w2.z + a.w*w3.z;
        acc[j].w += a.x*w0.w + a.y*w1.w + a.z*w2.w + a.w*w3.w;
      }
    }
    __syncthreads();
  }
  #pragma unroll
  for (int j = 0; j < 4; ++j){
    int row = m0 + rowg + 32*j;
    if (row < M){
      ushort4 o;
      o.x = f2bf(acc[j].x); o.y = f2bf(acc[j].y);
      o.z = f2bf(acc[j].z); o.w = f2bf(acc[j].w);
      *(ushort4*)(Out + (size_t)row*32 + c4) = o;
    }
  }
}

// ---------------- edge classifier (bf16 z-vectors) ----------------
__global__ __launch_bounds__(256) void k_edge(
    const int* __restrict__ el0, const int* __restrict__ el1,
    const int* __restrict__ sup1,
    const ushort* __restrict__ zt, const ushort* __restrict__ zpb,
    const ushort* __restrict__ zpc,
    const float* __restrict__ b1, const float* __restrict__ W2,
    const float* __restrict__ b2, float* __restrict__ out, int n){
  __shared__ float sW[32], sb[32];
  if (threadIdx.x < 32){ sW[threadIdx.x] = W2[threadIdx.x]; sb[threadIdx.x] = b1[threadIdx.x]; }
  __syncthreads();
  int e = blockIdx.x*256 + threadIdx.x;
  if (e >= n) return;
  int t = el0[e], p = el1[e];
  int m = sup1[t];
  const uint4* zr = (const uint4*)(zt  + (size_t)t*32);
  const uint4* br = (const uint4*)(zpb + (size_t)m*32);
  const uint4* cr = (const uint4*)(zpc + (size_t)p*32);
  float acc = 0.f;
  #pragma unroll
  for (int i = 0; i < 4; ++i){
    uint4 ua = zr[i], ub = br[i], uc = cr[i];
    const uint aw[4] = {ua.x, ua.y, ua.z, ua.w};
    const uint bw[4] = {ub.x, ub.y, ub.z, ub.w};
    const uint cw[4] = {uc.x, uc.y, uc.z, uc.w};
    #pragma unroll
    for (int k = 0; k < 4; ++k){
      int base = i*8 + k*2;
      float h0 = bf2f((ushort)(aw[k] & 0xffff)) + bf2f((ushort)(bw[k] & 0xffff))
               + bf2f((ushort)(cw[k] & 0xffff)) + sb[base];
      float h1 = bf2f((ushort)(aw[k] >> 16)) + bf2f((ushort)(bw[k] >> 16))
               + bf2f((ushort)(cw[k] >> 16)) + sb[base + 1];
      h0 = h0 > 0.f ? h0 : 0.f;
      h1 = h1 > 0.f ? h1 : 0.f;
      acc = fmaf(h0, sW[base], acc);
      acc = fmaf(h1, sW[base + 1], acc);
    }
  }
  out[e] = acc + b2[0];
}

// ---------------- launch ----------------
extern "C" void kernel_launch(void* const* d_in, const int* in_sizes, int n_in,
                              void* d_out, int out_size, void* d_ws, size_t ws_size,
                              hipStream_t stream){
  const float* thesis_x = (const float*)d_in[0];
  const float* lin_W    = (const float*)d_in[1];
  const float* lin_b    = (const float*)d_in[2];
  const float* prof_emb = (const float*)d_in[3];
  const float* gWl      = (const float*)d_in[4];
  const float* gbl      = (const float*)d_in[5];
  const float* gWr      = (const float*)d_in[6];
  const float* cW1      = (const float*)d_in[7];
  const float* cb1      = (const float*)d_in[8];
  const float* cW2      = (const float*)d_in[9];
  const float* cb2      = (const float*)d_in[10];
  const int*   pid      = (const int*)d_in[11];
  const int*   sup0     = (const int*)d_in[12];
  const int*   sup1     = sup0 + NT;
  const int*   com0     = (const int*)d_in[13];
  const int*   com1     = com0 + EC;
  const int*   el0      = (const int*)d_in[14];
  const int*   el1      = el0 + EL;
  float* outp = (float*)d_out;

  char* base = (char*)d_ws;
  size_t off = 0;
  auto alloc = [&](size_t bytes)->void*{
    void* p = base + off;
    off += (bytes + 255) & ~(size_t)255;
    return p;
  };
  ushort* xt     = (ushort*)alloc((size_t)NT*CDIM*2);   // bf16, permuted cols
  ushort* aggp   = (ushort*)alloc((size_t)NT*CDIM*2);   // bf16 permuted; zt aliases later
  float*  xp0    = (float*)alloc((size_t)NP*CDIM*4);
  float*  xp1    = (float*)alloc((size_t)NP*CDIM*4);
  float*  apcat  = (float*)alloc((size_t)NP*384*4);
  float*  yp2p   = (float*)alloc((size_t)NP*CDIM*4);
  float*  yp3p   = (float*)alloc((size_t)NP*CDIM*4);
  float*  Wp     = (float*)alloc((size_t)384*128*4);
  float*  bp     = (float*)alloc(512);
  float*  btp    = (float*)alloc(512);
  ushort* WmFrag = (ushort*)alloc((size_t)384*128*2);
  ushort* WtFrag = (ushort*)alloc((size_t)128*128*2);
  ushort* W1aFrag= (ushort*)alloc((size_t)128*32*2);
  ushort* zpb    = (ushort*)alloc((size_t)NP*32*2);
  ushort* zpc    = (ushort*)alloc((size_t)NP*32*2);
  int* rp_all  = (int*)alloc((size_t)(NKEYS+1)*4);
  int* vals    = (int*)alloc((size_t)NEDGE*4);
  int* counts  = (int*)alloc((size_t)NKEYS*4);
  int* cursor  = (int*)alloc((size_t)NKEYS*4);
  int* partials= (int*)alloc(4096);
  ushort* zt   = aggp;   // alias: aggp dead after layer-1 k_mm EPI

  auto cdiv = [](int a, int b){ return (a + b - 1)/b; };

  // ---- fused CSR build (7 launches) ----
  hipMemsetAsync(counts, 0, (size_t)NKEYS*4, stream);
  k_hist3<<<cdiv(NEDGE,256),256,0,stream>>>(com0, com1, sup1, counts);
  int nPb = cdiv(NKEYS,256);
  k_partial<<<nPb,256,0,stream>>>(counts, NKEYS, partials);
  k_scan_partials<<<1,1024,0,stream>>>(partials, nPb, rp_all + NKEYS);
  k_scan_final<<<nPb,256,0,stream>>>(counts, partials, NKEYS, rp_all);
  k_copy_int<<<cdiv(NKEYS,256),256,0,stream>>>(rp_all, cursor, NKEYS);
  k_fill3<<<cdiv(NEDGE,256),256,0,stream>>>(com0, com1, sup0, sup1, cursor, vals);
  const int* rp_t = rp_all;               // com by thesis (vals = prof)
  const int* crp  = rp_all + NT;          // com by prof (vals = thesis)
  const int* mrp  = rp_all + NT + NP;     // sup by prof (vals = thesis)

  // ---- prep: xp init + weight packs ----
  k_prep<<<cdiv(NP*CDIM + 384*128 + 128*32,256),256,0,stream>>>(
      prof_emb, pid, xp0, lin_W, WmFrag, cW1, W1aFrag);

  // xt = perm-bf16(thesis_x @ lin_W + lin_b)
  k_mm<384,true,false,false><<<cdiv(NT,128),256,0,stream>>>(
      thesis_x, NT, WmFrag, lin_b, xt, nullptr);

  float* xpo = xp0; float* xpn = xp1;
  for (int l = 0; l < 2; ++l){
    k_wcombine<<<64,256,0,stream>>>(gWl, gbl, gWr, l, Wp, bp, WtFrag, btp);
    k_segsum<<<cdiv(NP,4),256,0,stream>>>((const uint*)xt, xpo, mrp, crp, vals, apcat);
    k_gemm3<<<dim3(cdiv(NP,64),3),256,0,stream>>>(
        apcat, xpo, l, Wp, gWl, bp, xpn, yp2p, yp3p);
    k_agg<<<cdiv(NT,8),256,0,stream>>>(sup1, rp_t, vals, yp2p, yp3p, btp, aggp);
    if (l == 0)
      k_mm<128,false,true,true><<<cdiv(NT,128),256,0,stream>>>(
          xt, NT, WtFrag, nullptr, xt, aggp);
    else
      k_mm<128,false,true,false><<<cdiv(NT,128),256,0,stream>>>(
          xt, NT, WtFrag, nullptr, xt, aggp);
    float* tmp = xpo; xpo = xpn; xpn = tmp;
  }

  // classifier precomputes (zt aliases aggp — aggp fully consumed above)
  k_mm_n32<<<cdiv(NT,128),256,0,stream>>>(xt, NT, W1aFrag, zt);
  k_gemm32<<<dim3(cdiv(NP,128),2),256,0,stream>>>(
      xpo, NP, cW1 + 128*32, cW1 + 256*32, zpb, zpc);
  k_edge<<<cdiv(EL,256),256,0,stream>>>(el0, el1, sup1, zt, zpb, zpc,
                                        cb1, cW2, cb2, outp, EL);
}

// Round 6
// 940.631 us; speedup vs baseline: 2.4898x; 1.0868x over previous
//
#include <hip/hip_runtime.h>
#include <hip/hip_bf16.h>
#include <cstdint>
#include <cstddef>

#define NT 200000
#define NP 5000
#define FDIM 384
#define CDIM 128
#define EC 600000
#define EL 400000
#define NKEYS (NT + 2*NP)          // concatenated CSR segment count
#define NEDGE (2*EC + NT)          // concatenated edge count

typedef unsigned int uint;
typedef unsigned short ushort;
typedef __attribute__((ext_vector_type(8))) __bf16 bf16x8;
typedef __attribute__((ext_vector_type(4))) float f32x4;

union FragU { uint4 u; bf16x8 b; };

__device__ __forceinline__ ushort f2bf(float f){
  uint u = __float_as_uint(f);
  u = (u + 0x7fffu + ((u >> 16) & 1u)) >> 16;
  return (ushort)u;
}
__device__ __forceinline__ float bf2f(ushort h){
  return __uint_as_float(((uint)h) << 16);
}
// storage permutation: sigma(c) = (c&15)*8 + (c>>4); invs below
__device__ __forceinline__ int invs(int w){
  return ((w >> 2) & 1)*64 + (w & 3)*16 + (w >> 3);
}

// ---------------- fused CSR build ----------------
__global__ void k_hist3(const int* __restrict__ com0, const int* __restrict__ com1,
                        const int* __restrict__ sup1, int* __restrict__ counts){
  int i = blockIdx.x*256 + threadIdx.x;
  if (i < EC)            atomicAdd(&counts[com0[i]], 1);
  else if (i < 2*EC)     atomicAdd(&counts[NT + com1[i - EC]], 1);
  else if (i < NEDGE)    atomicAdd(&counts[NT + NP + sup1[i - 2*EC]], 1);
}

// local exclusive scan per 256-block + block totals
__global__ void k_scanA(const int* __restrict__ counts, int n,
                        int* __restrict__ rowptr, int* __restrict__ partials){
  __shared__ int s[256];
  int tid = threadIdx.x;
  int i = blockIdx.x*256 + tid;
  int v = (i < n) ? counts[i] : 0;
  s[tid] = v; __syncthreads();
  for (int off = 1; off < 256; off <<= 1){
    int t = (tid >= off) ? s[tid - off] : 0;
    __syncthreads();
    s[tid] += t;
    __syncthreads();
  }
  if (i < n) rowptr[i] = s[tid] - v;
  if (tid == 255) partials[blockIdx.x] = s[255];
}

__global__ void k_scanB(int* __restrict__ partials, int nP, int* __restrict__ total_out){
  __shared__ int s[1024];
  int carry = 0;
  for (int base = 0; base < nP; base += 1024){
    int i = base + threadIdx.x;
    int v = (i < nP) ? partials[i] : 0;
    s[threadIdx.x] = v; __syncthreads();
    for (int off = 1; off < 1024; off <<= 1){
      int t = (threadIdx.x >= off) ? s[threadIdx.x - off] : 0;
      __syncthreads();
      s[threadIdx.x] += t;
      __syncthreads();
    }
    if (i < nP) partials[i] = carry + s[threadIdx.x] - v;
    int chunk_total = s[1023];
    __syncthreads();
    carry += chunk_total;
  }
  if (threadIdx.x == 0 && total_out) *total_out = carry;
}

__global__ void k_scanC(int* __restrict__ rowptr, const int* __restrict__ pscan,
                        int n, int* __restrict__ cursor){
  int i = blockIdx.x*256 + threadIdx.x;
  if (i < n){
    int r = rowptr[i] + pscan[i >> 8];
    rowptr[i] = r;
    cursor[i] = r;
  }
}

__global__ void k_fill3(const int* __restrict__ com0, const int* __restrict__ com1,
                        const int* __restrict__ sup0, const int* __restrict__ sup1,
                        int* __restrict__ cursor, int* __restrict__ vals){
  int i = blockIdx.x*256 + threadIdx.x;
  int key, sv;
  if (i < EC)          { key = com0[i];                 sv = com1[i]; }
  else if (i < 2*EC)   { key = NT + com1[i - EC];       sv = com0[i - EC]; }
  else if (i < NEDGE)  { key = NT + NP + sup1[i - 2*EC]; sv = sup0[i - 2*EC]; }
  else return;
  int pos = atomicAdd(&cursor[key], 1);
  vals[pos] = sv;
}

// ---------------- prep: xp0 sigma-bf16 + WmFrag(natural) + W1aFrag(invs) + Wzb/WzcPerm ----------
__global__ void k_prep(const float* __restrict__ pe, const int* __restrict__ pid,
                       ushort* __restrict__ xp0,
                       const float* __restrict__ lin_W, ushort* __restrict__ WmFrag,
                       const float* __restrict__ cW1, ushort* __restrict__ W1aFrag,
                       float* __restrict__ WzbPerm, float* __restrict__ WzcPerm){
  int i = blockIdx.x*256 + threadIdx.x;
  if (i < NP*CDIM){                     // xp0[p][w] = bf16(pe[pid[p]][invs(w)])
    int p = i >> 7, w = i & 127;
    xp0[i] = f2bf(pe[(size_t)pid[p]*CDIM + invs(w)]);
    return;
  }
  i -= NP*CDIM;
  if (i < 384*128){                     // natural pack (A = fp32 natural)
    int j = i & 7, lane = (i >> 3) & 63, q = lane >> 4, nl = lane & 15, tl = i >> 9;
    int nt = tl & 7, kc = tl >> 3;
    int k = kc*32 + q*8 + j, n = nt*16 + nl;
    WmFrag[i] = f2bf(lin_W[(size_t)k*128 + n]);
    return;
  }
  i -= 384*128;
  if (i < 128*32){                      // invs pack (A = sigma-stored), N=32
    int j = i & 7, lane = (i >> 3) & 63, q = lane >> 4, nl = lane & 15, tl = i >> 9;
    int nt = tl & 1, kc = tl >> 1;
    int s = 32*kc + 8*q + j, n = nt*16 + nl;
    W1aFrag[i] = f2bf(cW1[(size_t)invs(s)*32 + n]);
    return;
  }
  i -= 128*32;
  if (i < 2*128*32){                    // row-permuted fp32 W for gemm32
    int m = i >> 12;                    // 0 = zpb block, 1 = zpc block
    int o = i & 4095;
    int s = o >> 5, n = o & 31;
    float v = cW1[(size_t)(128 + m*128 + invs(s))*32 + n];
    (m ? WzcPerm : WzbPerm)[o] = v;
  }
}

// ---------------- per-layer weight prep: WpFrag, Wl2Frag, Wl3Frag, WtFrag, bp, btp ----------------
__global__ void k_wprep(const float* __restrict__ gWl, const float* __restrict__ gbl,
                        const float* __restrict__ gWr, int layer,
                        ushort* __restrict__ WpFrag, ushort* __restrict__ Wl2Frag,
                        ushort* __restrict__ Wl3Frag, ushort* __restrict__ WtFrag,
                        float* __restrict__ bp, float* __restrict__ btp){
  int i = blockIdx.x*256 + threadIdx.x;
  const float* Wl_l = gWl + (size_t)layer*4*16384;
  const float* Wr_l = gWr + (size_t)layer*4*16384;
  const float* bl_l = gbl + (size_t)layer*4*128;
  if (i < 49152){                       // WpFrag: K=384, all blocks invs (A = [sig|sig|sig])
    int j = i & 7, lane = (i >> 3) & 63, q = lane >> 4, nl = lane & 15, tl = i >> 9;
    int nt = tl & 7, kc = tl >> 3;      // kc 0..11
    int s_row = 32*kc + 8*q + j;
    int b = s_row >> 7, w = s_row & 127;
    int r = invs(w), n = nt*16 + nl;
    float v;
    if (b == 0)      v = Wl_l[(size_t)r*128 + n];
    else if (b == 1) v = Wl_l[16384 + (size_t)r*128 + n];
    else             v = Wr_l[(size_t)r*128 + n] + Wr_l[16384 + (size_t)r*128 + n];
    WpFrag[i] = f2bf(v);
    return;
  }
  i -= 49152;
  if (i < 3*16384){                     // Wl2 / Wl3 / Wt frags (K=128, invs)
    int m = i >> 14;                    // 0,1,2
    int o = i & 16383;
    int j = o & 7, lane = (o >> 3) & 63, q = lane >> 4, nl = lane & 15, tl = o >> 9;
    int nt = tl & 7, kc = tl >> 3;      // kc 0..3
    int s = 32*kc + 8*q + j;
    int r = invs(s), n = nt*16 + nl;
    float v;
    if (m == 0)      v = Wl_l[2*16384 + (size_t)r*128 + n];
    else if (m == 1) v = Wl_l[3*16384 + (size_t)r*128 + n];
    else             v = Wr_l[2*16384 + (size_t)r*128 + n] + Wr_l[3*16384 + (size_t)r*128 + n];
    (m == 0 ? Wl2Frag : (m == 1 ? Wl3Frag : WtFrag))[o] = f2bf(v);
    return;
  }
  i -= 3*16384;
  if (i < 128){
    bp[i] = bl_l[i] + bl_l[128 + i];
    btp[(i & 15)*8 + (i >> 4)] = bl_l[2*128 + i] + bl_l[3*128 + i];   // sigma store
  }
}

// ---------------- segment sums: wave per prof; xt/xp sigma-bf16 in, apcat sigma-bf16 out --------
__global__ __launch_bounds__(256) void k_segsum(
    const uint* __restrict__ xt32, const uint* __restrict__ xp32,
    const int* __restrict__ mrp, const int* __restrict__ crp,
    const int* __restrict__ vall, uint* __restrict__ apcat){
  int p = blockIdx.x*4 + (threadIdx.x >> 6);
  if (p >= NP) return;
  int lane = threadIdx.x & 63;
  float s0a = 0.f, s0b = 0.f;
  {
    int j = mrp[p], je = mrp[p+1];
    for (; j + 4 <= je; j += 4){
      uint v0 = xt32[(size_t)vall[j]  *64 + lane];
      uint v1 = xt32[(size_t)vall[j+1]*64 + lane];
      uint v2 = xt32[(size_t)vall[j+2]*64 + lane];
      uint v3 = xt32[(size_t)vall[j+3]*64 + lane];
      s0a += (bf2f((ushort)(v0 & 0xffff)) + bf2f((ushort)(v1 & 0xffff)))
           + (bf2f((ushort)(v2 & 0xffff)) + bf2f((ushort)(v3 & 0xffff)));
      s0b += (bf2f((ushort)(v0 >> 16)) + bf2f((ushort)(v1 >> 16)))
           + (bf2f((ushort)(v2 >> 16)) + bf2f((ushort)(v3 >> 16)));
    }
    for (; j < je; ++j){
      uint v = xt32[(size_t)vall[j]*64 + lane];
      s0a += bf2f((ushort)(v & 0xffff));
      s0b += bf2f((ushort)(v >> 16));
    }
  }
  float s1a = 0.f, s1b = 0.f;
  {
    int j = crp[p], je = crp[p+1];
    for (; j + 4 <= je; j += 4){
      uint v0 = xt32[(size_t)vall[j]  *64 + lane];
      uint v1 = xt32[(size_t)vall[j+1]*64 + lane];
      uint v2 = xt32[(size_t)vall[j+2]*64 + lane];
      uint v3 = xt32[(size_t)vall[j+3]*64 + lane];
      s1a += (bf2f((ushort)(v0 & 0xffff)) + bf2f((ushort)(v1 & 0xffff)))
           + (bf2f((ushort)(v2 & 0xffff)) + bf2f((ushort)(v3 & 0xffff)));
      s1b += (bf2f((ushort)(v0 >> 16)) + bf2f((ushort)(v1 >> 16)))
           + (bf2f((ushort)(v2 >> 16)) + bf2f((ushort)(v3 >> 16)));
    }
    for (; j < je; ++j){
      uint v = xt32[(size_t)vall[j]*64 + lane];
      s1a += bf2f((ushort)(v & 0xffff));
      s1b += bf2f((ushort)(v >> 16));
    }
  }
  uint* row = apcat + (size_t)p*192;
  row[lane]       = (uint)f2bf(s0a) | ((uint)f2bf(s0b) << 16);
  row[64 + lane]  = (uint)f2bf(s1a) | ((uint)f2bf(s1b) << 16);
  row[128 + lane] = xp32[(size_t)p*64 + lane];
}

// ---------------- edge aggregation (bf16 sigma tables) ----------------
__global__ __launch_bounds__(256) void k_agg(
    const int* __restrict__ mentor, const int* __restrict__ rowptr,
    const int* __restrict__ vals,
    const ushort* __restrict__ yp2p, const ushort* __restrict__ yp3p,
    const float* __restrict__ btp, ushort* __restrict__ aggp){
  int t = blockIdx.x*8 + (threadIdx.x >> 5);
  if (t >= NT) return;
  int i = threadIdx.x & 31;
  float4 s = *(const float4*)(btp + i*4);
  int m = mentor[t];
  ushort4 y = *(const ushort4*)(yp2p + (size_t)m*CDIM + i*4);
  s.x += bf2f(y.x); s.y += bf2f(y.y); s.z += bf2f(y.z); s.w += bf2f(y.w);
  int qb = rowptr[t], qe = rowptr[t+1];
  for (int q = qb; q < qe; ++q){
    ushort4 z = *(const ushort4*)(yp3p + (size_t)vals[q]*CDIM + i*4);
    s.x += bf2f(z.x); s.y += bf2f(z.y); s.z += bf2f(z.z); s.w += bf2f(z.w);
  }
  ushort4 o;
  o.x = f2bf(s.x); o.y = f2bf(s.y); o.z = f2bf(s.z); o.w = f2bf(s.w);
  *(ushort4*)(aggp + (size_t)t*CDIM + i*4) = o;
}

// ---------------- thesis MFMA GEMM ----------------
// ZT: skip xt store; round-trip tile through LDS (stride 136) and emit zt = tile @ W1a
template<int K, bool AF32, bool EPI, bool RELU, bool ZT>
__global__ __launch_bounds__(256) void k_mm(
    const void* __restrict__ Ain, int M,
    const ushort* __restrict__ Wfrag, const float* __restrict__ bias,
    ushort* __restrict__ Outp, const ushort* __restrict__ aggp,
    const ushort* __restrict__ W1a, ushort* __restrict__ ztout){
  constexpr int SMSZ = ZT ? 2176 : 1024;      // uint4 units (ZT: 34816 B tile overlay)
  __shared__ uint4 smem[SMSZ];
  uint4* As = smem;
  uint4* Bs = smem + 512;
  ushort* tile = (ushort*)smem;               // 128 x 136, used after K-loop only
  const int tid  = threadIdx.x;
  const int lane = tid & 63;
  const int wave = tid >> 6;
  const int wr   = wave >> 1, wc = wave & 1;
  const int m0   = blockIdx.x * 128;
  const float* Af = (const float*)Ain;
  const ushort* Ab = (const ushort*)Ain;

  f32x4 acc[4][4];
  #pragma unroll
  for (int i = 0; i < 4; ++i)
    #pragma unroll
    for (int j = 0; j < 4; ++j) acc[i][j] = (f32x4)(0.f);

  for (int kc = 0; kc < K/32; ++kc){
    if (AF32){
      const int rs = tid >> 2, qs = tid & 3;
      #pragma unroll
      for (int h = 0; h < 2; ++h){
        int rr = rs + 64*h;
        int grow = m0 + rr;
        uint4 payload = make_uint4(0,0,0,0);
        if (grow < M){
          const float* ap = Af + (size_t)grow*K + kc*32 + qs*8;
          float4 fa = *(const float4*)ap;
          float4 fb = *(const float4*)(ap + 4);
          payload.x = (uint)f2bf(fa.x) | ((uint)f2bf(fa.y) << 16);
          payload.y = (uint)f2bf(fa.z) | ((uint)f2bf(fa.w) << 16);
          payload.z = (uint)f2bf(fb.x) | ((uint)f2bf(fb.y) << 16);
          payload.w = (uint)f2bf(fb.z) | ((uint)f2bf(fb.w) << 16);
        }
        As[(rr >> 4)*64 + qs*16 + (rr & 15)] = payload;
      }
    } else {
      #pragma unroll
      for (int h = 0; h < 2; ++h){
        int e = tid + 256*h;
        int rr = e >> 2, q = e & 3;
        int grow = m0 + rr;
        uint4 payload = make_uint4(0,0,0,0);
        if (grow < M)
          payload = *(const uint4*)(Ab + (size_t)grow*K + (4*kc + q)*8);
        As[(rr >> 4)*64 + q*16 + (rr & 15)] = payload;
      }
    }
    const uint4* wsrc = (const uint4*)Wfrag + (size_t)kc*512;
    Bs[tid]       = wsrc[tid];
    Bs[tid + 256] = wsrc[tid + 256];
    __syncthreads();

    bf16x8 a[4], b[4];
    #pragma unroll
    for (int i = 0; i < 4; ++i){ FragU u; u.u = As[(wr*4 + i)*64 + lane]; a[i] = u.b; }
    #pragma unroll
    for (int j = 0; j < 4; ++j){ FragU u; u.u = Bs[(wc*4 + j)*64 + lane]; b[j] = u.b; }
    #pragma unroll
    for (int i = 0; i < 4; ++i)
      #pragma unroll
      for (int j = 0; j < 4; ++j)
        acc[i][j] = __builtin_amdgcn_mfma_f32_16x16x32_bf16(a[i], b[j], acc[i][j], 0, 0, 0);
    __syncthreads();
  }

  // --- epilogue ---
  const int nl = lane & 15;
  float bv[4];
  #pragma unroll
  for (int j = 0; j < 4; ++j) bv[j] = bias ? bias[wc*64 + j*16 + nl] : 0.f;
  const int s0 = nl*8 + wc*4;

  #pragma unroll
  for (int i = 0; i < 4; ++i){
    int rb = wr*64 + i*16 + (lane >> 4)*4;
    #pragma unroll
    for (int reg = 0; reg < 4; ++reg){
      int rr = rb + reg;
      int row = m0 + rr;
      if (row >= M) continue;
      float v0 = acc[i][0][reg] + bv[0];
      float v1 = acc[i][1][reg] + bv[1];
      float v2 = acc[i][2][reg] + bv[2];
      float v3 = acc[i][3][reg] + bv[3];
      if (EPI){
        ushort4 av = *(const ushort4*)(aggp + (size_t)row*CDIM + s0);
        v0 += bf2f(av.x); v1 += bf2f(av.y); v2 += bf2f(av.z); v3 += bf2f(av.w);
      }
      if (RELU){
        v0 = v0 > 0.f ? v0 : 0.f; v1 = v1 > 0.f ? v1 : 0.f;
        v2 = v2 > 0.f ? v2 : 0.f; v3 = v3 > 0.f ? v3 : 0.f;
      }
      ushort4 o;
      o.x = f2bf(v0); o.y = f2bf(v1); o.z = f2bf(v2); o.w = f2bf(v3);
      if (ZT) *(ushort4*)&tile[(size_t)rr*136 + s0] = o;
      else    *(ushort4*)(Outp + (size_t)row*CDIM + s0) = o;
    }
  }

  if (ZT){
    __syncthreads();
    const uint4* wf = (const uint4*)W1a;
    const int q = lane >> 4, mm = lane & 15;
    f32x4 acc2[2][2];
    #pragma unroll
    for (int a2 = 0; a2 < 2; ++a2)
      #pragma unroll
      for (int b2 = 0; b2 < 2; ++b2) acc2[a2][b2] = (f32x4)(0.f);
    #pragma unroll
    for (int kc = 0; kc < 4; ++kc){
      bf16x8 af[2];
      #pragma unroll
      for (int i2 = 0; i2 < 2; ++i2){
        FragU u;
        u.u = *(const uint4*)&tile[(size_t)(wave*32 + i2*16 + mm)*136 + (4*kc + q)*8];
        af[i2] = u.b;
      }
      #pragma unroll
      for (int nt = 0; nt < 2; ++nt){
        FragU u; u.u = wf[(kc*2 + nt)*64 + lane];
        #pragma unroll
        for (int i2 = 0; i2 < 2; ++i2)
          acc2[i2][nt] = __builtin_amdgcn_mfma_f32_16x16x32_bf16(af[i2], u.b, acc2[i2][nt], 0, 0, 0);
      }
    }
    #pragma unroll
    for (int i2 = 0; i2 < 2; ++i2){
      #pragma unroll
      for (int reg = 0; reg < 4; ++reg){
        int row = m0 + wave*32 + i2*16 + q*4 + reg;
        if (row >= M) continue;
        ztout[(size_t)row*32 + mm]      = f2bf(acc2[i2][0][reg]);
        ztout[(size_t)row*32 + 16 + mm] = f2bf(acc2[i2][1][reg]);
      }
    }
  }
}

// ---------------- prof MFMA GEMM: y = {xp-update(K=384), yp2, yp3} ----------------
__global__ __launch_bounds__(256) void k_mmp(
    const ushort* __restrict__ apcat, const ushort* __restrict__ xpold, int layer,
    const ushort* __restrict__ WpFrag, const ushort* __restrict__ Wl2Frag,
    const ushort* __restrict__ Wl3Frag, const float* __restrict__ bp,
    ushort* __restrict__ xpnew, ushort* __restrict__ yp2p, ushort* __restrict__ yp3p){
  const int y = blockIdx.y;
  const ushort* A; const ushort* Wf; const float* bias; ushort* Out;
  int nkc, rowlen; bool relu;
  if (y == 0){ A = apcat; rowlen = 384; nkc = 12; Wf = WpFrag; bias = bp;
               Out = xpnew; relu = (layer == 0); }
  else if (y == 1){ A = xpold; rowlen = 128; nkc = 4; Wf = Wl2Frag; bias = nullptr;
               Out = yp2p; relu = false; }
  else       { A = xpold; rowlen = 128; nkc = 4; Wf = Wl3Frag; bias = nullptr;
               Out = yp3p; relu = false; }

  __shared__ uint4 As[512];
  __shared__ uint4 Bs[512];
  const int tid  = threadIdx.x;
  const int lane = tid & 63;
  const int wave = tid >> 6;
  const int wr   = wave >> 1, wc = wave & 1;
  const int m0   = blockIdx.x * 128;

  f32x4 acc[4][4];
  #pragma unroll
  for (int i = 0; i < 4; ++i)
    #pragma unroll
    for (int j = 0; j < 4; ++j) acc[i][j] = (f32x4)(0.f);

  for (int kc = 0; kc < nkc; ++kc){
    #pragma unroll
    for (int h = 0; h < 2; ++h){
      int e = tid + 256*h;
      int rr = e >> 2, q = e & 3;
      int grow = m0 + rr;
      uint4 payload = make_uint4(0,0,0,0);
      if (grow < NP)
        payload = *(const uint4*)(A + (size_t)grow*rowlen + (4*kc + q)*8);
      As[(rr >> 4)*64 + q*16 + (rr & 15)] = payload;
    }
    const uint4* wsrc = (const uint4*)Wf + (size_t)kc*512;
    Bs[tid]       = wsrc[tid];
    Bs[tid + 256] = wsrc[tid + 256];
    __syncthreads();

    bf16x8 a[4], b[4];
    #pragma unroll
    for (int i = 0; i < 4; ++i){ FragU u; u.u = As[(wr*4 + i)*64 + lane]; a[i] = u.b; }
    #pragma unroll
    for (int j = 0; j < 4; ++j){ FragU u; u.u = Bs[(wc*4 + j)*64 + lane]; b[j] = u.b; }
    #pragma unroll
    for (int i = 0; i < 4; ++i)
      #pragma unroll
      for (int j = 0; j < 4; ++j)
        acc[i][j] = __builtin_amdgcn_mfma_f32_16x16x32_bf16(a[i], b[j], acc[i][j], 0, 0, 0);
    __syncthreads();
  }

  const int nl = lane & 15;
  float bv[4];
  #pragma unroll
  for (int j = 0; j < 4; ++j) bv[j] = bias ? bias[wc*64 + j*16 + nl] : 0.f;
  const int s0 = nl*8 + wc*4;

  #pragma unroll
  for (int i = 0; i < 4; ++i){
    int r0 = m0 + wr*64 + i*16 + (lane >> 4)*4;
    #pragma unroll
    for (int reg = 0; reg < 4; ++reg){
      int row = r0 + reg;
      if (row >= NP) continue;
      float v0 = acc[i][0][reg] + bv[0];
      float v1 = acc[i][1][reg] + bv[1];
      float v2 = acc[i][2][reg] + bv[2];
      float v3 = acc[i][3][reg] + bv[3];
      if (relu){
        v0 = v0 > 0.f ? v0 : 0.f; v1 = v1 > 0.f ? v1 : 0.f;
        v2 = v2 > 0.f ? v2 : 0.f; v3 = v3 > 0.f ? v3 : 0.f;
      }
      ushort4 o;
      o.x = f2bf(v0); o.y = f2bf(v1); o.z = f2bf(v2); o.w = f2bf(v3);
      *(ushort4*)(Out + (size_t)row*CDIM + s0) = o;
    }
  }
}

// ---------------- N=32 GEMM (prof zpb/zpc): A sigma-bf16, W row-permuted fp32 ----------------
__global__ __launch_bounds__(256) void k_gemm32(const ushort* __restrict__ A, int M,
                                                const float* __restrict__ W0,
                                                const float* __restrict__ W1,
                                                ushort* __restrict__ Out0,
                                                ushort* __restrict__ Out1){
  const float* W = blockIdx.y ? W1 : W0;
  ushort* Out = blockIdx.y ? Out1 : Out0;
  __shared__ float As[128*36];
  __shared__ float Ws[32*32];
  const int tid  = threadIdx.x;
  const int m0   = blockIdx.x*128;
  const int c4   = (tid & 7)*4;
  const int rowg = tid >> 3;
  float4 acc[4];
  #pragma unroll
  for (int j = 0; j < 4; ++j) acc[j] = make_float4(0.f,0.f,0.f,0.f);

  for (int k0 = 0; k0 < 128; k0 += 32){
    #pragma unroll
    for (int l = 0; l < 4; ++l){
      int q = tid + 256*l;
      int r = q >> 3, kf = q & 7;
      int row = m0 + r;
      float4 v = make_float4(0.f,0.f,0.f,0.f);
      if (row < M){
        ushort4 u = *(const ushort4*)(A + (size_t)row*CDIM + k0 + kf*4);
        v = make_float4(bf2f(u.x), bf2f(u.y), bf2f(u.z), bf2f(u.w));
      }
      *(float4*)&As[r*36 + kf*4] = v;
    }
    {
      int kk = tid >> 3, cf = tid & 7;
      *(float4*)&Ws[kk*32 + cf*4] = *(const float4*)(W + (size_t)(k0+kk)*32 + cf*4);
    }
    __syncthreads();
    #pragma unroll
    for (int k4 = 0; k4 < 8; ++k4){
      float4 w0 = *(const float4*)&Ws[(k4*4+0)*32 + c4];
      float4 w1 = *(const float4*)&Ws[(k4*4+1)*32 + c4];
      float4 w2 = *(const float4*)&Ws[(k4*4+2)*32 + c4];
      float4 w3 = *(const float4*)&Ws[(k4*4+3)*32 + c4];
      #pragma unroll
      for (int j = 0; j < 4; ++j){
        float4 a = *(const float4*)&As[(rowg + 32*j)*36 + k4*4];
        acc[j].x += a.x*w0.x + a.y*w1.x + a.z*w2.x + a.w*w3.x;
        acc[j].y += a.x*w0.y + a.y*w1.y + a.z*w2.y + a.w*w3.y;
        acc[j].z += a.x*w0.z + a.y*w1.z + a.z*w2.z + a.w*w3.z;
        acc[j].w += a.x*w0.w + a.y*w1.w + a.z*w2.w + a.w*w3.w;
      }
    }
    __syncthreads();
  }
  #pragma unroll
  for (int j = 0; j < 4; ++j){
    int row = m0 + rowg + 32*j;
    if (row < M){
      ushort4 o;
      o.x = f2bf(acc[j].x); o.y = f2bf(acc[j].y);
      o.z = f2bf(acc[j].z); o.w = f2bf(acc[j].w);
      *(ushort4*)(Out + (size_t)row*32 + c4) = o;
    }
  }
}

// ---------------- edge classifier ----------------
__global__ __launch_bounds__(256) void k_edge(
    const int* __restrict__ el0, const int* __restrict__ el1,
    const int* __restrict__ sup1,
    const ushort* __restrict__ zt, const ushort* __restrict__ zpb,
    const ushort* __restrict__ zpc,
    const float* __restrict__ b1, const float* __restrict__ W2,
    const float* __restrict__ b2, float* __restrict__ out, int n){
  __shared__ float sW[32], sb[32];
  if (threadIdx.x < 32){ sW[threadIdx.x] = W2[threadIdx.x]; sb[threadIdx.x] = b1[threadIdx.x]; }
  __syncthreads();
  int e = blockIdx.x*256 + threadIdx.x;
  if (e >= n) return;
  int t = el0[e], p = el1[e];
  int m = sup1[t];
  const uint4* zr = (const uint4*)(zt  + (size_t)t*32);
  const uint4* br = (const uint4*)(zpb + (size_t)m*32);
  const uint4* cr = (const uint4*)(zpc + (size_t)p*32);
  float acc = 0.f;
  #pragma unroll
  for (int i = 0; i < 4; ++i){   // 4 uint4 = 32 bf16 hidden units (R5 bug: was i<2)
    uint4 ua = zr[i], ub = br[i], uc = cr[i];
    const uint aw[4] = {ua.x, ua.y, ua.z, ua.w};
    const uint bw[4] = {ub.x, ub.y, ub.z, ub.w};
    const uint cw[4] = {uc.x, uc.y, uc.z, uc.w};
    #pragma unroll
    for (int k = 0; k < 4; ++k){
      int base = i*8 + k*2;
      float h0 = bf2f((ushort)(aw[k] & 0xffff)) + bf2f((ushort)(bw[k] & 0xffff))
               + bf2f((ushort)(cw[k] & 0xffff)) + sb[base];
      float h1 = bf2f((ushort)(aw[k] >> 16)) + bf2f((ushort)(bw[k] >> 16))
               + bf2f((ushort)(cw[k] >> 16)) + sb[base + 1];
      h0 = h0 > 0.f ? h0 : 0.f;
      h1 = h1 > 0.f ? h1 : 0.f;
      acc = fmaf(h0, sW[base], acc);
      acc = fmaf(h1, sW[base + 1], acc);
    }
  }
  out[e] = acc + b2[0];
}

// ---------------- launch ----------------
extern "C" void kernel_launch(void* const* d_in, const int* in_sizes, int n_in,
                              void* d_out, int out_size, void* d_ws, size_t ws_size,
                              hipStream_t stream){
  const float* thesis_x = (const float*)d_in[0];
  const float* lin_W    = (const float*)d_in[1];
  const float* lin_b    = (const float*)d_in[2];
  const float* prof_emb = (const float*)d_in[3];
  const float* gWl      = (const float*)d_in[4];
  const float* gbl      = (const float*)d_in[5];
  const float* gWr      = (const float*)d_in[6];
  const float* cW1      = (const float*)d_in[7];
  const float* cb1      = (const float*)d_in[8];
  const float* cW2      = (const float*)d_in[9];
  const float* cb2      = (const float*)d_in[10];
  const int*   pid      = (const int*)d_in[11];
  const int*   sup0     = (const int*)d_in[12];
  const int*   sup1     = sup0 + NT;
  const int*   com0     = (const int*)d_in[13];
  const int*   com1     = com0 + EC;
  const int*   el0      = (const int*)d_in[14];
  const int*   el1      = el0 + EL;
  float* outp = (float*)d_out;

  char* base = (char*)d_ws;
  size_t off = 0;
  auto alloc = [&](size_t bytes)->void*{
    void* p = base + off;
    off += (bytes + 255) & ~(size_t)255;
    return p;
  };
  ushort* xt      = (ushort*)alloc((size_t)NT*CDIM*2);   // sigma-bf16
  ushort* aggp    = (ushort*)alloc((size_t)NT*CDIM*2);   // sigma-bf16
  ushort* zt      = (ushort*)alloc((size_t)NT*32*2);     // natural bf16
  ushort* xp0     = (ushort*)alloc((size_t)NP*CDIM*2);   // sigma-bf16
  ushort* xp1     = (ushort*)alloc((size_t)NP*CDIM*2);
  ushort* apcat   = (ushort*)alloc((size_t)NP*384*2);    // [sig|sig|sig] bf16
  ushort* yp2p    = (ushort*)alloc((size_t)NP*CDIM*2);
  ushort* yp3p    = (ushort*)alloc((size_t)NP*CDIM*2);
  ushort* WmFrag  = (ushort*)alloc((size_t)384*128*2);
  ushort* W1aFrag = (ushort*)alloc((size_t)128*32*2);
  float*  WzbPerm = (float*)alloc((size_t)128*32*4);
  float*  WzcPerm = (float*)alloc((size_t)128*32*4);
  ushort* WpFrag  = (ushort*)alloc((size_t)2*384*128*2);
  ushort* Wl2Frag = (ushort*)alloc((size_t)2*128*128*2);
  ushort* Wl3Frag = (ushort*)alloc((size_t)2*128*128*2);
  ushort* WtFrag  = (ushort*)alloc((size_t)2*128*128*2);
  float*  bp      = (float*)alloc(2*512);
  float*  btp     = (float*)alloc(2*512);
  ushort* zpb     = (ushort*)alloc((size_t)NP*32*2);
  ushort* zpc     = (ushort*)alloc((size_t)NP*32*2);
  int* rp_all  = (int*)alloc((size_t)(NKEYS+1)*4);
  int* vals    = (int*)alloc((size_t)NEDGE*4);
  int* counts  = (int*)alloc((size_t)NKEYS*4);
  int* cursor  = (int*)alloc((size_t)NKEYS*4);
  int* partials= (int*)alloc(8192);

  auto cdiv = [](int a, int b){ return (a + b - 1)/b; };

  // ---- CSR build (6 dispatches) ----
  hipMemsetAsync(counts, 0, (size_t)NKEYS*4, stream);
  k_hist3<<<cdiv(NEDGE,256),256,0,stream>>>(com0, com1, sup1, counts);
  int nPb = cdiv(NKEYS,256);
  k_scanA<<<nPb,256,0,stream>>>(counts, NKEYS, rp_all, partials);
  k_scanB<<<1,1024,0,stream>>>(partials, nPb, rp_all + NKEYS);
  k_scanC<<<nPb,256,0,stream>>>(rp_all, partials, NKEYS, cursor);
  k_fill3<<<cdiv(NEDGE,256),256,0,stream>>>(com0, com1, sup0, sup1, cursor, vals);
  const int* rp_t = rp_all;               // com by thesis (vals = prof)
  const int* crp  = rp_all + NT;          // com by prof (vals = thesis)
  const int* mrp  = rp_all + NT + NP;     // sup by prof (vals = thesis)

  // ---- prep ----
  k_prep<<<cdiv(NP*CDIM + 384*128 + 128*32 + 2*128*32,256),256,0,stream>>>(
      prof_emb, pid, xp0, lin_W, WmFrag, cW1, W1aFrag, WzbPerm, WzcPerm);
  for (int l = 0; l < 2; ++l)
    k_wprep<<<cdiv(49152 + 3*16384 + 128,256),256,0,stream>>>(
        gWl, gbl, gWr, l,
        WpFrag + (size_t)l*49152, Wl2Frag + (size_t)l*16384,
        Wl3Frag + (size_t)l*16384, WtFrag + (size_t)l*16384,
        bp + l*128, btp + l*128);

  // xt = sigma-bf16(thesis_x @ lin_W + lin_b)
  k_mm<384,true,false,false,false><<<cdiv(NT,128),256,0,stream>>>(
      thesis_x, NT, WmFrag, lin_b, xt, nullptr, nullptr, nullptr);

  ushort* xpo = xp0; ushort* xpn = xp1;
  for (int l = 0; l < 2; ++l){
    k_segsum<<<cdiv(NP,4),256,0,stream>>>((const uint*)xt, (const uint*)xpo,
                                          mrp, crp, vals, (uint*)apcat);
    k_mmp<<<dim3(cdiv(NP,128),3),256,0,stream>>>(
        apcat, xpo, l, WpFrag + (size_t)l*49152, Wl2Frag + (size_t)l*16384,
        Wl3Frag + (size_t)l*16384, bp + l*128, xpn, yp2p, yp3p);
    k_agg<<<cdiv(NT,8),256,0,stream>>>(sup1, rp_t, vals, yp2p, yp3p, btp + l*128, aggp);
    if (l == 0)
      k_mm<128,false,true,true,false><<<cdiv(NT,128),256,0,stream>>>(
          xt, NT, WtFrag, nullptr, xt, aggp, nullptr, nullptr);
    else
      k_mm<128,false,true,false,true><<<cdiv(NT,128),256,0,stream>>>(
          xt, NT, WtFrag + 16384, nullptr, nullptr, aggp, W1aFrag, zt);
    ushort* tmp = xpo; xpo = xpn; xpn = tmp;
  }

  k_gemm32<<<dim3(cdiv(NP,128),2),256,0,stream>>>(
      xpo, NP, WzbPerm, WzcPerm, zpb, zpc);
  k_edge<<<cdiv(EL,256),256,0,stream>>>(el0, el1, sup1, zt, zpb, zpc,
                                        cb1, cW2, cb2, outp, EL);
}